// Round 8
// baseline (351.880 us; speedup 1.0000x reference)
//
#include <hip/hip_runtime.h>

// Problem constants
#define B_    2
#define S_    2048
#define HID_  1536
#define NH_   12
#define NKV_  2
#define HD_   128
#define GRP_  6
#define NQKV_ 2048

// converted-input region layout (element offsets)
#define CV_HS  0
#define CV_QW  6291456
#define CV_KW  8650752
#define CV_VW  9043968
#define CV_OW  9437184
#define CV_TOT 11796480

typedef __attribute__((ext_vector_type(8))) short bf16x8;
typedef __attribute__((ext_vector_type(4))) short bf16x4;
typedef __attribute__((ext_vector_type(4))) float f32x4;

__device__ __forceinline__ float bf2f(unsigned short u) {
    union { unsigned int i; float f; } v; v.i = ((unsigned int)u) << 16; return v.f;
}
__device__ __forceinline__ unsigned short f2bf(float f) {
    union { float f; unsigned int i; } v; v.f = f;
    unsigned int r = v.i + 0x7fffu + ((v.i >> 16) & 1u);  // RNE
    return (unsigned short)(r >> 16);
}

__device__ __forceinline__ void gload_lds16(const unsigned short* g, unsigned short* l) {
    __builtin_amdgcn_global_load_lds(
        (const __attribute__((address_space(1))) void*)g,
        (__attribute__((address_space(3))) void*)l, 16, 0, 0);
}
__device__ __forceinline__ void gload_lds16b(const char* g, char* l) {
    __builtin_amdgcn_global_load_lds(
        (const __attribute__((address_space(1))) void*)g,
        (__attribute__((address_space(3))) void*)l, 16, 0, 0);
}

// 16x16x16 bf16 MFMA (PV step): builtin name varies across ROCm versions.
#if __has_builtin(__builtin_amdgcn_mfma_f32_16x16x16bf16_1k)
__device__ __forceinline__ f32x4 mfma16(bf16x4 a, bf16x4 b, f32x4 c) {
    return __builtin_amdgcn_mfma_f32_16x16x16bf16_1k(a, b, c, 0, 0, 0);
}
#elif __has_builtin(__builtin_amdgcn_mfma_f32_16x16x16_bf16)
__device__ __forceinline__ f32x4 mfma16(bf16x4 a, bf16x4 b, f32x4 c) {
    return __builtin_amdgcn_mfma_f32_16x16x16_bf16(a, b, c, 0, 0, 0);
}
#else
__device__ __forceinline__ f32x4 mfma16(bf16x4 a, bf16x4 b, f32x4 c) {
    asm volatile("v_mfma_f32_16x16x16_bf16 %0, %1, %2, %0"
                 : "+v"(c) : "v"(a), "v"(b));
    return c;
}
#endif

// ---------------------------------------------------------------------------
// dtype detection: flag 0 = bf16, 1 = f32.
// ---------------------------------------------------------------------------
__global__ void detect_dtype(const unsigned short* __restrict__ hs, int* __restrict__ flag) {
    const int i = threadIdx.x;                  // 64 threads
    const unsigned short u = hs[2 * i];
    const int e = (u >> 7) & 0xFF;
    const bool sane = (e >= 96 && e <= 143);    // |x| in [2^-31, 2^16]
    const unsigned long long m = __ballot(sane);
    if (i == 0) flag[0] = (__popcll(m) < 32) ? 1 : 0;
}

// 8 elements per thread; all region boundaries are multiples of 8.
__global__ __launch_bounds__(256) void convert_inputs(
    const void* __restrict__ hs, const void* __restrict__ qw,
    const void* __restrict__ kw, const void* __restrict__ vw,
    const void* __restrict__ ow, const int* __restrict__ flag,
    unsigned short* __restrict__ dst)
{
    const size_t idx = ((size_t)blockIdx.x * 256 + threadIdx.x) * 8;
    if (idx >= CV_TOT) return;
    const void* p; size_t j;
    if (idx < CV_QW)      { p = hs; j = idx; }
    else if (idx < CV_KW) { p = qw; j = idx - CV_QW; }
    else if (idx < CV_VW) { p = kw; j = idx - CV_KW; }
    else if (idx < CV_OW) { p = vw; j = idx - CV_VW; }
    else                  { p = ow; j = idx - CV_OW; }
    if (flag[0]) {
        const float* src = (const float*)p + j;
        const float4 f0 = *(const float4*)(src);
        const float4 f1 = *(const float4*)(src + 4);
        uint4 o;
        o.x = (unsigned int)f2bf(f0.x) | ((unsigned int)f2bf(f0.y) << 16);
        o.y = (unsigned int)f2bf(f0.z) | ((unsigned int)f2bf(f0.w) << 16);
        o.z = (unsigned int)f2bf(f1.x) | ((unsigned int)f2bf(f1.y) << 16);
        o.w = (unsigned int)f2bf(f1.z) | ((unsigned int)f2bf(f1.w) << 16);
        *(uint4*)(dst + idx) = o;
    } else {
        *(uint4*)(dst + idx) = *(const uint4*)((const unsigned short*)p + j);
    }
}

// ---------------------------------------------------------------------------
// GEMM QKV: C[m,n] = sum_k A[m,k]*W[n,k] + bias. dbuf single-barrier loop.
// ---------------------------------------------------------------------------
__global__ __launch_bounds__(256) void gemm_qkv(
    const unsigned short* __restrict__ A,     // bf16 hidden [4096,1536]
    const unsigned short* __restrict__ Wall,  // bf16 region base (qw/kw/vw)
    const void* __restrict__ qb, const void* __restrict__ kb,
    const void* __restrict__ vb, const int* __restrict__ flag,
    unsigned short* __restrict__ C)           // [4096,2048] bf16
{
    __shared__ unsigned short As[2][128 * 32];
    __shared__ unsigned short Ws[2][128 * 32];
    const int tid = threadIdx.x;
    const int w = tid >> 6, lane = tid & 63, quad = lane >> 4, l16 = lane & 15;
    const int wr = w >> 1, wc = w & 1;
    const int n0 = blockIdx.x * 128;
    const int m0 = blockIdx.y * 128;
    const int flg = flag[0];

    const unsigned short* Wp; const void* bias; int boff;
    if (n0 < 1536)      { Wp = Wall + CV_QW + (size_t)n0 * HID_;          bias = qb; boff = n0; }
    else if (n0 < 1792) { Wp = Wall + CV_KW + (size_t)(n0 - 1536) * HID_; bias = kb; boff = n0 - 1536; }
    else                { Wp = Wall + CV_VW + (size_t)(n0 - 1792) * HID_; bias = vb; boff = n0 - 1792; }

    f32x4 acc[4][4];
#pragma unroll
    for (int i = 0; i < 4; i++)
#pragma unroll
        for (int j = 0; j < 4; j++) acc[i][j] = (f32x4)0.0f;

    const int c0 = w * 64, c1 = 256 + w * 64;
    const int ca = c0 + lane, cb = c1 + lane;
    const int rA0 = ca >> 2, pA0 = (ca & 3) * 8;
    const int rA1 = cb >> 2, pA1 = (cb & 3) * 8;

#define STAGEG(bufi, kt)                                                          \
    do {                                                                          \
        const int k0_ = (kt) * 32;                                                \
        gload_lds16(A  + (size_t)(m0 + rA0) * HID_ + k0_ + pA0, &As[bufi][c0*8]); \
        gload_lds16(A  + (size_t)(m0 + rA1) * HID_ + k0_ + pA1, &As[bufi][c1*8]); \
        gload_lds16(Wp + (size_t)rA0 * HID_ + k0_ + pA0, &Ws[bufi][c0*8]);        \
        gload_lds16(Wp + (size_t)rA1 * HID_ + k0_ + pA1, &Ws[bufi][c1*8]);        \
    } while (0)

    int cur = 0;
    STAGEG(0, 0);
    __syncthreads();                              // buf0 staged

    for (int kt = 0; kt < HID_ / 32; ++kt) {
        if (kt + 1 < HID_ / 32) STAGEG(cur ^ 1, kt + 1);   // flies under compute

        bf16x8 a[4], b[4];
#pragma unroll
        for (int mi = 0; mi < 4; mi++)
            a[mi] = *(const bf16x8*)&As[cur][(wr * 64 + mi * 16 + l16) * 32 + quad * 8];
#pragma unroll
        for (int ni = 0; ni < 4; ni++)
            b[ni] = *(const bf16x8*)&Ws[cur][(wc * 64 + ni * 16 + l16) * 32 + quad * 8];
#pragma unroll
        for (int mi = 0; mi < 4; mi++)
#pragma unroll
            for (int ni = 0; ni < 4; ni++)
                acc[mi][ni] = __builtin_amdgcn_mfma_f32_16x16x32_bf16(a[mi], b[ni], acc[mi][ni], 0, 0, 0);

        __syncthreads();                          // next-buf DMA drained; reads done
        cur ^= 1;
    }
#undef STAGEG

#pragma unroll
    for (int mi = 0; mi < 4; mi++) {
        const int row = m0 + wr * 64 + mi * 16 + quad * 4;
#pragma unroll
        for (int ni = 0; ni < 4; ni++) {
            const int cl = wc * 64 + ni * 16 + l16;
            const float bv = flg ? ((const float*)bias)[boff + cl]
                                 : bf2f(((const unsigned short*)bias)[boff + cl]);
#pragma unroll
            for (int r = 0; r < 4; r++)
                C[(size_t)(row + r) * NQKV_ + n0 + cl] = f2bf(acc[mi][ni][r] + bv);
        }
    }
}

__global__ __launch_bounds__(256) void gemm_o(
    const unsigned short* __restrict__ A,   // attn_out [4096,1536] bf16
    const unsigned short* __restrict__ W,   // o_w bf16 [1536,1536]
    const int* __restrict__ flag,
    void* __restrict__ C)                   // out [4096,1536] bf16 or f32
{
    __shared__ unsigned short As[2][128 * 32];
    __shared__ unsigned short Ws[2][128 * 32];
    const int tid = threadIdx.x;
    const int w = tid >> 6, lane = tid & 63, quad = lane >> 4, l16 = lane & 15;
    const int wr = w >> 1, wc = w & 1;
    const int n0 = blockIdx.x * 128;
    const int m0 = blockIdx.y * 128;
    const int flg = flag[0];
    const unsigned short* Wp = W + (size_t)n0 * HID_;

    f32x4 acc[4][4];
#pragma unroll
    for (int i = 0; i < 4; i++)
#pragma unroll
        for (int j = 0; j < 4; j++) acc[i][j] = (f32x4)0.0f;

    const int c0 = w * 64, c1 = 256 + w * 64;
    const int ca = c0 + lane, cb = c1 + lane;
    const int rA0 = ca >> 2, pA0 = (ca & 3) * 8;
    const int rA1 = cb >> 2, pA1 = (cb & 3) * 8;

#define STAGEG(bufi, kt)                                                          \
    do {                                                                          \
        const int k0_ = (kt) * 32;                                                \
        gload_lds16(A  + (size_t)(m0 + rA0) * HID_ + k0_ + pA0, &As[bufi][c0*8]); \
        gload_lds16(A  + (size_t)(m0 + rA1) * HID_ + k0_ + pA1, &As[bufi][c1*8]); \
        gload_lds16(Wp + (size_t)rA0 * HID_ + k0_ + pA0, &Ws[bufi][c0*8]);        \
        gload_lds16(Wp + (size_t)rA1 * HID_ + k0_ + pA1, &Ws[bufi][c1*8]);        \
    } while (0)

    int cur = 0;
    STAGEG(0, 0);
    __syncthreads();

    for (int kt = 0; kt < HID_ / 32; ++kt) {
        if (kt + 1 < HID_ / 32) STAGEG(cur ^ 1, kt + 1);

        bf16x8 a[4], b[4];
#pragma unroll
        for (int mi = 0; mi < 4; mi++)
            a[mi] = *(const bf16x8*)&As[cur][(wr * 64 + mi * 16 + l16) * 32 + quad * 8];
#pragma unroll
        for (int ni = 0; ni < 4; ni++)
            b[ni] = *(const bf16x8*)&Ws[cur][(wc * 64 + ni * 16 + l16) * 32 + quad * 8];
#pragma unroll
        for (int mi = 0; mi < 4; mi++)
#pragma unroll
            for (int ni = 0; ni < 4; ni++)
                acc[mi][ni] = __builtin_amdgcn_mfma_f32_16x16x32_bf16(a[mi], b[ni], acc[mi][ni], 0, 0, 0);

        __syncthreads();
        cur ^= 1;
    }
#undef STAGEG

#pragma unroll
    for (int mi = 0; mi < 4; mi++) {
        const int row = m0 + wr * 64 + mi * 16 + quad * 4;
#pragma unroll
        for (int ni = 0; ni < 4; ni++) {
            const int col = n0 + wc * 64 + ni * 16 + l16;
#pragma unroll
            for (int r = 0; r < 4; r++) {
                const size_t off = (size_t)(row + r) * HID_ + col;
                if (flg) ((float*)C)[off] = acc[mi][ni][r];
                else ((unsigned short*)C)[off] = f2bf(acc[mi][ni][r]);
            }
        }
    }
}

// ---------------------------------------------------------------------------
// mrope + scatter (cos/sin read flag-adaptively from original inputs)
// Q is scaled by 1/sqrt(128) * log2(e): attention uses exp2-domain softmax.
// ---------------------------------------------------------------------------
__global__ __launch_bounds__(256) void rope_scatter(
    const unsigned short* __restrict__ Cqkv,
    const void* __restrict__ cosp, const void* __restrict__ sinp,
    const int* __restrict__ flag,
    unsigned short* __restrict__ Q,           // [B,NH,S,HD]
    unsigned short* __restrict__ K,           // [B,NKV,S,HD]
    unsigned short* __restrict__ Vt)          // [B,NKV,HD,S]
{
    const int idx = blockIdx.x * 256 + threadIdx.x;
    const int m = idx >> 11, col = idx & 2047;
    const int b = m >> 11, s = m & 2047;
    const unsigned short raw = Cqkv[(size_t)m * NQKV_ + col];
    if (col < 1792) {
        const int d = col & 127;
        const int dd = d & 63;
        const int axis = dd < 16 ? 0 : (dd < 40 ? 1 : 2);
        const size_t cidx = (((size_t)axis * B_ + b) * S_ + s) * HD_ + d;
        const int flg = flag[0];
        const float cs = flg ? ((const float*)cosp)[cidx] : bf2f(((const unsigned short*)cosp)[cidx]);
        const float sn = flg ? ((const float*)sinp)[cidx] : bf2f(((const unsigned short*)sinp)[cidx]);
        const float x  = bf2f(raw);
        const float xp = bf2f(Cqkv[(size_t)m * NQKV_ + (col ^ 64)]);
        float y = (d < 64) ? (x * cs - xp * sn) : (x * cs + xp * sn);
        if (col < 1536) {
            const int h = col >> 7;
            y *= 0.1275174313431108f;   // 1/sqrt(128) * log2(e) folded into Q
            Q[(((size_t)b * NH_ + h) * S_ + s) * HD_ + d] = f2bf(y);
        } else {
            const int kv = (col - 1536) >> 7;
            K[(((size_t)b * NKV_ + kv) * S_ + s) * HD_ + d] = f2bf(y);
        }
    } else {
        const int cv = col - 1792;
        const int kv = cv >> 7, d = cv & 127;
        Vt[(((size_t)b * NKV_ + kv) * HD_ + d) * S_ + s] = raw;
    }
}

// ---------------------------------------------------------------------------
// Flash attention v6: v4 tile structure + SPLIT-K on heavy q-tiles.
// Grid (24, 48): y<32 -> qt = 16+(y>>1), chunk y&1 (k-range halved, f32
// partial O/m/l written to scratch); y>=32 -> qt = 47-y, single chunk,
// final output written directly. Critical path 32 -> ~17 k-tiles.
// Scratch placement (ZERO footprint growth vs round-6's verified layout):
//   Opart0 -> dead CV_HS conv region (384*8192 f32 = exact fit)
//   Opart1 -> d_out used as scratch (>= 12.58 MB both dtypes; consumed by
//             attn_combine before gemm_o overwrites d_out)
//   mlp    -> dead qw-conv region (conv + CV_QW, 0.39 of 4.7 MB)
// ---------------------------------------------------------------------------
__global__ __launch_bounds__(256, 3) void attn_fwd(
    const unsigned short* __restrict__ Q,
    const unsigned short* __restrict__ K,
    const unsigned short* __restrict__ Vt,
    float* __restrict__ Opart0,          // [384][64][128] f32 (CV_HS reuse)
    float* __restrict__ Opart1,          // [384][64][128] f32 (d_out scratch)
    float* __restrict__ mlp,             // [384][2][2][64] f32 (m,l per chunk)
    unsigned short* __restrict__ Aout)   // [4096, 1536]
{
    __shared__ unsigned short Ks2[2][64 * 128];   // linear, swizzled content
    __shared__ unsigned short Vs1[128 * 64];      // linear, swizzled content

    const int tid = threadIdx.x;
    const int w = tid >> 6, lane = tid & 63, quad = lane >> 4, l16 = lane & 15;
    const int bh = blockIdx.x;              // 0..23
    const int y  = blockIdx.y;              // 0..47
    int qt, t0, t1, chunk; bool split;
    if (y < 32) {                            // heavy tiles, split in two
        split = true;
        qt = 16 + (y >> 1);
        chunk = y & 1;
        const int half = (qt + 1) >> 1;
        t0 = chunk ? half : 0;
        t1 = chunk ? (qt + 1) : half;
    } else {                                 // light tiles, single chunk
        split = false; chunk = 0;
        qt = 47 - y;
        t0 = 0; t1 = qt + 1;
    }
    const int h  = bh % NH_;
    const int b  = bh / NH_;
    const int kvh = h / GRP_;
    const int q0 = qt * 64;

    const unsigned short* Qp = Q  + (((size_t)b * NH_ + h) * S_ + q0) * HD_;
    const char* Kg = (const char*)(K  + ((size_t)b * NKV_ + kvh) * S_ * HD_);
    const char* Vg = (const char*)(Vt + ((size_t)b * NKV_ + kvh) * HD_ * S_);

    // Q fragments in registers: row q = l16, k-chunk quad*8 (B-operand of QK^T)
    bf16x8 aq[4];
    {
        const unsigned short* qr = Qp + (size_t)(w * 16 + l16) * HD_ + quad * 8;
#pragma unroll
        for (int ks = 0; ks < 4; ks++)
            aq[ks] = *(const bf16x8*)(qr + ks * 32);
    }

    // Per-lane pre-swizzled source byte offsets for the DMA chunks.
    int offK[4], offV[4];
#pragma unroll
    for (int i = 0; i < 4; i++) {
        const int cK = w * 4 + i;
        const int krow = cK * 4 + (lane >> 4);
        const int kc = (lane & 15) * 16;
        offK[i] = krow * 256 + (kc ^ ((krow & 7) << 4));
        const int cV = w * 4 + i;
        const int vrow = cV * 8 + (lane >> 3);
        const int vc = (lane & 7) * 16;
        offV[i] = vrow * 4096 + (vc ^ ((vrow & 7) << 4));
    }

#define STAGE_K(bufi, tt)                                                      \
    do {                                                                       \
        char* kd_ = (char*)&Ks2[bufi][0];                                      \
        _Pragma("unroll")                                                      \
        for (int i_ = 0; i_ < 4; i_++)                                         \
            gload_lds16b(Kg + (tt) * 16384 + offK[i_],                         \
                         kd_ + (w * 4 + i_) * 1024);                           \
    } while (0)
#define STAGE_V(tt)                                                            \
    do {                                                                       \
        char* vd_ = (char*)&Vs1[0];                                            \
        _Pragma("unroll")                                                      \
        for (int i_ = 0; i_ < 4; i_++)                                         \
            gload_lds16b(Vg + (tt) * 128 + offV[i_],                           \
                         vd_ + (w * 4 + i_) * 1024);                           \
    } while (0)

    f32x4 Ot[8];                         // O^T fragments: row d, col q=l16
#pragma unroll
    for (int i = 0; i < 8; i++) Ot[i] = (f32x4)0.0f;
    float m_st = -1e30f, l_st = 0.f;     // lane-local (q = l16)

    const int xorb = (l16 & 7) << 4;     // read-side swizzle (row&7 == l16&7)
    int cur = 0;

    STAGE_K(0, t0);
    __syncthreads();      // vmcnt(0) drain at barrier -> K[t0] staged

    for (int t = t0; t < t1; t++) {
        const int k0 = t * 64;
        STAGE_V(t);                                // lands at B1
        if (t + 1 < t1) STAGE_K(cur ^ 1, t + 1);   // lands at B1 (early, ok)

        const char* kb_ = (const char*)&Ks2[cur][0];

        // S^T = K * Q^T : rows k (A = K-frag), cols q (B = Q-frag).
        f32x4 Sf[4];
#pragma unroll
        for (int i = 0; i < 4; i++) Sf[i] = (f32x4)0.0f;
        __builtin_amdgcn_s_setprio(1);
#pragma unroll
        for (int ks = 0; ks < 4; ks++) {
#pragma unroll
            for (int ni = 0; ni < 4; ni++) {
                bf16x8 bk = *(const bf16x8*)(kb_ + (ni * 16 + l16) * 256 +
                                             ((ks * 64 + quad * 16) ^ xorb));
                Sf[ni] = __builtin_amdgcn_mfma_f32_16x16x32_bf16(bk, aq[ks], Sf[ni], 0, 0, 0);
            }
        }
        __builtin_amdgcn_s_setprio(0);

        // causal mask only on the diagonal tile (t == qt; never in chunk 0)
        if (t == qt) {
            const int qq = q0 + w * 16 + l16;
#pragma unroll
            for (int ni = 0; ni < 4; ni++)
#pragma unroll
                for (int r = 0; r < 4; r++) {
                    const int kk = k0 + ni * 16 + quad * 4 + r;
                    if (kk > qq) Sf[ni][r] = -1e9f;
                }
        }

        // lane-local online softmax (exp2 domain; log2e folded into Q)
        float mx = Sf[0][0];
#pragma unroll
        for (int ni = 0; ni < 4; ni++)
#pragma unroll
            for (int r = 0; r < 4; r++) mx = fmaxf(mx, Sf[ni][r]);
        mx = fmaxf(mx, __shfl_xor(mx, 16, 64));
        mx = fmaxf(mx, __shfl_xor(mx, 32, 64));
        const float mn = fmaxf(m_st, mx);
        const float alpha = exp2f(m_st - mn);
        m_st = mn;
        float ps = 0.f;
#pragma unroll
        for (int ni = 0; ni < 4; ni++)
#pragma unroll
            for (int r = 0; r < 4; r++) {
                const float p = exp2f(Sf[ni][r] - mn);
                Sf[ni][r] = p;
                ps += p;
            }
        ps += __shfl_xor(ps, 16, 64);
        ps += __shfl_xor(ps, 32, 64);
        l_st = l_st * alpha + ps;
#pragma unroll
        for (int di = 0; di < 8; di++)
#pragma unroll
            for (int r = 0; r < 4; r++) Ot[di][r] *= alpha;

        __syncthreads();   // B1: V[t] (and K[t+1]) landed

        // O^T += V^T * P^T  (A = V^T-frag from LDS, B = P^T from S^T C-frag)
        const char* vb_ = (const char*)&Vs1[0];
        __builtin_amdgcn_s_setprio(1);
#pragma unroll
        for (int ni = 0; ni < 4; ni++) {
            bf16x4 pa;
            pa[0] = (short)f2bf(Sf[ni][0]);
            pa[1] = (short)f2bf(Sf[ni][1]);
            pa[2] = (short)f2bf(Sf[ni][2]);
            pa[3] = (short)f2bf(Sf[ni][3]);
#pragma unroll
            for (int di = 0; di < 8; di++) {
                bf16x4 va = *(const bf16x4*)(vb_ + (di * 16 + l16) * 128 +
                                             ((ni * 32 + quad * 8) ^ xorb));
                Ot[di] = mfma16(va, pa, Ot[di]);
            }
        }
        __builtin_amdgcn_s_setprio(0);

        __syncthreads();   // B2: all Vs reads done before next STAGE_V
        cur ^= 1;
    }
#undef STAGE_K
#undef STAGE_V

    const int rowl = w * 16 + l16;           // local q-row (0..63)
    if (!split) {
        // Ot[di][r]: d = di*16 + quad*4 + r, q = l16 (l_st lane-local)
        const float rl = 1.0f / l_st;
        const int qrow = q0 + rowl;
        unsigned short* dst = Aout + ((size_t)b * S_ + qrow) * HID_ + h * HD_;
#pragma unroll
        for (int di = 0; di < 8; di++) {
            ushort4 o;
            o.x = f2bf(Ot[di][0] * rl);
            o.y = f2bf(Ot[di][1] * rl);
            o.z = f2bf(Ot[di][2] * rl);
            o.w = f2bf(Ot[di][3] * rl);
            *(ushort4*)(dst + di * 16 + quad * 4) = o;
        }
    } else {
        const int pair = bh * 16 + (qt - 16);          // 0..383
        float* Ob = (chunk ? Opart1 : Opart0) + (size_t)pair * 8192;
#pragma unroll
        for (int di = 0; di < 8; di++)
            *(f32x4*)&Ob[rowl * 128 + di * 16 + quad * 4] = Ot[di];
        if (quad == 0) {
            mlp[pair * 256 + chunk * 128 + rowl]      = m_st;
            mlp[pair * 256 + chunk * 128 + 64 + rowl] = l_st;
        }
    }
}

// ---------------------------------------------------------------------------
// Combine the two split-K partials per heavy q-tile; write bf16 into Aout.
// ---------------------------------------------------------------------------
__global__ __launch_bounds__(256) void attn_combine(
    const float* __restrict__ Opart0, const float* __restrict__ Opart1,
    const float* __restrict__ mlp, unsigned short* __restrict__ Aout)
{
    const int pair = blockIdx.x;             // 0..383
    const int bh = pair >> 4;
    const int qt = 16 + (pair & 15);
    const int h = bh % NH_, b = bh / NH_;
    const int q0 = qt * 64;
    const int row = threadIdx.x >> 2;        // 0..63
    const int dseg = (threadIdx.x & 3) * 32; // 0,32,64,96

    const float m0 = mlp[pair * 256 + row],       l0 = mlp[pair * 256 + 64 + row];
    const float m1 = mlp[pair * 256 + 128 + row], l1 = mlp[pair * 256 + 192 + row];
    const float m = fmaxf(m0, m1);
    const float s0 = exp2f(m0 - m), s1 = exp2f(m1 - m);
    const float rl = 1.0f / (l0 * s0 + l1 * s1);

    const float* O0 = Opart0 + (size_t)pair * 8192 + row * 128 + dseg;
    const float* O1 = Opart1 + (size_t)pair * 8192 + row * 128 + dseg;
    unsigned short* dst = Aout + ((size_t)b * S_ + q0 + row) * HID_ + h * HD_ + dseg;
#pragma unroll
    for (int j = 0; j < 32; j += 4) {
        const float4 a = *(const float4*)(O0 + j);
        const float4 c = *(const float4*)(O1 + j);
        ushort4 o;
        o.x = f2bf((a.x * s0 + c.x * s1) * rl);
        o.y = f2bf((a.y * s0 + c.y * s1) * rl);
        o.z = f2bf((a.z * s0 + c.z * s1) * rl);
        o.w = f2bf((a.w * s0 + c.w * s1) * rl);
        *(ushort4*)(dst + j) = o;
    }
}

extern "C" void kernel_launch(void* const* d_in, const int* in_sizes, int n_in,
                              void* d_out, int out_size, void* d_ws, size_t ws_size,
                              hipStream_t stream) {
    const void* hs   = d_in[0];
    const void* qw   = d_in[1];
    const void* qb   = d_in[2];
    const void* kw   = d_in[3];
    const void* kb   = d_in[4];
    const void* vw   = d_in[5];
    const void* vb   = d_in[6];
    const void* ow   = d_in[7];
    const void* cosp = d_in[8];
    const void* sinp = d_in[9];

    int* flag = (int*)d_ws;                                       // 16 shorts reserved
    unsigned short* conv = (unsigned short*)d_ws + 16;            // CV_TOT = 11796480
    unsigned short* Cqkv = conv + CV_TOT;                         // 8388608
    unsigned short* Qb   = Cqkv + (size_t)8388608;                // 6291456
    unsigned short* Kb   = Qb + (size_t)6291456;                  // 1048576
    unsigned short* Vtb  = Kb + (size_t)1048576;                  // 1048576
    unsigned short* Ao   = Cqkv;                                  // reuse (dead after rope)
    // Split-K partials — all in memory dead at attn time, zero footprint growth:
    //   chunk0 -> dead CV_HS conv region (384*8192 f32 = 3,145,728 f32 exact)
    //   chunk1 -> d_out scratch (>= 12.58 MB for both output dtypes; consumed
    //             by attn_combine before gemm_o rewrites d_out)
    //   m/l    -> dead qw conv region (98,304 f32 of 2,359,296-short region)
    float* Opart0 = (float*)conv;
    float* Opart1 = (float*)d_out;
    float* mlp    = (float*)(conv + CV_QW);

    detect_dtype<<<1, 64, 0, stream>>>((const unsigned short*)hs, flag);
    convert_inputs<<<(CV_TOT / 8 + 255) / 256, 256, 0, stream>>>(hs, qw, kw, vw, ow, flag, conv);
    gemm_qkv<<<dim3(16, 32), 256, 0, stream>>>(conv + CV_HS, conv, qb, kb, vb, flag, Cqkv);
    rope_scatter<<<dim3((4096 * 2048) / 256), 256, 0, stream>>>(Cqkv, cosp, sinp, flag, Qb, Kb, Vtb);
    attn_fwd<<<dim3(24, 48), 256, 0, stream>>>(Qb, Kb, Vtb, Opart0, Opart1, mlp, Ao);
    attn_combine<<<dim3(384), 256, 0, stream>>>(Opart0, Opart1, mlp, Ao);
    gemm_o<<<dim3(12, 32), 256, 0, stream>>>(Ao, conv + CV_OW, flag, d_out);
}

// Round 9
// 330.712 us; speedup vs baseline: 1.0640x; 1.0640x over previous
//
#include <hip/hip_runtime.h>

// Problem constants
#define B_    2
#define S_    2048
#define HID_  1536
#define NH_   12
#define NKV_  2
#define HD_   128
#define GRP_  6
#define NQKV_ 2048

// converted-input region layout (element offsets)
#define CV_HS  0
#define CV_QW  6291456
#define CV_KW  8650752
#define CV_VW  9043968
#define CV_OW  9437184
#define CV_TOT 11796480

typedef __attribute__((ext_vector_type(8))) short bf16x8;
typedef __attribute__((ext_vector_type(4))) short bf16x4;
typedef __attribute__((ext_vector_type(4))) float f32x4;

__device__ __forceinline__ float bf2f(unsigned short u) {
    union { unsigned int i; float f; } v; v.i = ((unsigned int)u) << 16; return v.f;
}
__device__ __forceinline__ unsigned short f2bf(float f) {
    union { float f; unsigned int i; } v; v.f = f;
    unsigned int r = v.i + 0x7fffu + ((v.i >> 16) & 1u);  // RNE
    return (unsigned short)(r >> 16);
}

__device__ __forceinline__ void gload_lds16(const unsigned short* g, unsigned short* l) {
    __builtin_amdgcn_global_load_lds(
        (const __attribute__((address_space(1))) void*)g,
        (__attribute__((address_space(3))) void*)l, 16, 0, 0);
}
__device__ __forceinline__ void gload_lds16b(const char* g, char* l) {
    __builtin_amdgcn_global_load_lds(
        (const __attribute__((address_space(1))) void*)g,
        (__attribute__((address_space(3))) void*)l, 16, 0, 0);
}

// 16x16x16 bf16 MFMA (PV step): builtin name varies across ROCm versions.
#if __has_builtin(__builtin_amdgcn_mfma_f32_16x16x16bf16_1k)
__device__ __forceinline__ f32x4 mfma16(bf16x4 a, bf16x4 b, f32x4 c) {
    return __builtin_amdgcn_mfma_f32_16x16x16bf16_1k(a, b, c, 0, 0, 0);
}
#elif __has_builtin(__builtin_amdgcn_mfma_f32_16x16x16_bf16)
__device__ __forceinline__ f32x4 mfma16(bf16x4 a, bf16x4 b, f32x4 c) {
    return __builtin_amdgcn_mfma_f32_16x16x16_bf16(a, b, c, 0, 0, 0);
}
#else
__device__ __forceinline__ f32x4 mfma16(bf16x4 a, bf16x4 b, f32x4 c) {
    asm volatile("v_mfma_f32_16x16x16_bf16 %0, %1, %2, %0"
                 : "+v"(c) : "v"(a), "v"(b));
    return c;
}
#endif

// ---------------------------------------------------------------------------
// dtype detection: flag 0 = bf16, 1 = f32.
// ---------------------------------------------------------------------------
__global__ void detect_dtype(const unsigned short* __restrict__ hs, int* __restrict__ flag) {
    const int i = threadIdx.x;                  // 64 threads
    const unsigned short u = hs[2 * i];
    const int e = (u >> 7) & 0xFF;
    const bool sane = (e >= 96 && e <= 143);    // |x| in [2^-31, 2^16]
    const unsigned long long m = __ballot(sane);
    if (i == 0) flag[0] = (__popcll(m) < 32) ? 1 : 0;
}

// 8 elements per thread; all region boundaries are multiples of 8.
__global__ __launch_bounds__(256) void convert_inputs(
    const void* __restrict__ hs, const void* __restrict__ qw,
    const void* __restrict__ kw, const void* __restrict__ vw,
    const void* __restrict__ ow, const int* __restrict__ flag,
    unsigned short* __restrict__ dst)
{
    const size_t idx = ((size_t)blockIdx.x * 256 + threadIdx.x) * 8;
    if (idx >= CV_TOT) return;
    const void* p; size_t j;
    if (idx < CV_QW)      { p = hs; j = idx; }
    else if (idx < CV_KW) { p = qw; j = idx - CV_QW; }
    else if (idx < CV_VW) { p = kw; j = idx - CV_KW; }
    else if (idx < CV_OW) { p = vw; j = idx - CV_VW; }
    else                  { p = ow; j = idx - CV_OW; }
    if (flag[0]) {
        const float* src = (const float*)p + j;
        const float4 f0 = *(const float4*)(src);
        const float4 f1 = *(const float4*)(src + 4);
        uint4 o;
        o.x = (unsigned int)f2bf(f0.x) | ((unsigned int)f2bf(f0.y) << 16);
        o.y = (unsigned int)f2bf(f0.z) | ((unsigned int)f2bf(f0.w) << 16);
        o.z = (unsigned int)f2bf(f1.x) | ((unsigned int)f2bf(f1.y) << 16);
        o.w = (unsigned int)f2bf(f1.z) | ((unsigned int)f2bf(f1.w) << 16);
        *(uint4*)(dst + idx) = o;
    } else {
        *(uint4*)(dst + idx) = *(const uint4*)((const unsigned short*)p + j);
    }
}

// ---------------------------------------------------------------------------
// GEMM QKV + fused mrope/scatter. C[m,n] = sum_k A[m,k]*W[n,k] + bias.
// Each 128-col N-tile is exactly one head: n0<1536 -> Q head n0>>7;
// 1536/1664 -> K heads; 1792/1920 -> V heads. Epilogue stashes the bf16
// C-tile in LDS (reuses staging LDS), then applies mrope and writes Q/K
// (Q scaled by 1/sqrt(128)*log2e) or the V [HD][S] transpose directly.
// ---------------------------------------------------------------------------
__global__ __launch_bounds__(256) void gemm_qkv(
    const unsigned short* __restrict__ A,     // bf16 hidden [4096,1536]
    const unsigned short* __restrict__ Wall,  // bf16 region base (qw/kw/vw)
    const void* __restrict__ qb, const void* __restrict__ kb,
    const void* __restrict__ vb,
    const void* __restrict__ cosp, const void* __restrict__ sinp,
    const int* __restrict__ flag,
    unsigned short* __restrict__ Q,           // [B,NH,S,HD]
    unsigned short* __restrict__ K,           // [B,NKV,S,HD]
    unsigned short* __restrict__ Vt)          // [B,NKV,HD,S]
{
    __shared__ char sm[34816];                           // staging / C-stash union
    unsigned short (*As)[4096] = (unsigned short (*)[4096])sm;            // [2][4096]
    unsigned short (*Ws)[4096] = (unsigned short (*)[4096])(sm + 16384);  // [2][4096]
    unsigned short (*Ct)[136]  = (unsigned short (*)[136])sm;             // [128][136]

    const int tid = threadIdx.x;
    const int w = tid >> 6, lane = tid & 63, quad = lane >> 4, l16 = lane & 15;
    const int wr = w >> 1, wc = w & 1;
    const int n0 = blockIdx.x * 128;
    const int m0 = blockIdx.y * 128;
    const int flg = flag[0];

    const unsigned short* Wp; const void* bias; int boff;
    if (n0 < 1536)      { Wp = Wall + CV_QW + (size_t)n0 * HID_;          bias = qb; boff = n0; }
    else if (n0 < 1792) { Wp = Wall + CV_KW + (size_t)(n0 - 1536) * HID_; bias = kb; boff = n0 - 1536; }
    else                { Wp = Wall + CV_VW + (size_t)(n0 - 1792) * HID_; bias = vb; boff = n0 - 1792; }

    f32x4 acc[4][4];
#pragma unroll
    for (int i = 0; i < 4; i++)
#pragma unroll
        for (int j = 0; j < 4; j++) acc[i][j] = (f32x4)0.0f;

    const int c0 = w * 64, c1 = 256 + w * 64;
    const int ca = c0 + lane, cb = c1 + lane;
    const int rA0 = ca >> 2, pA0 = (ca & 3) * 8;
    const int rA1 = cb >> 2, pA1 = (cb & 3) * 8;

#define STAGEG(bufi, kt)                                                          \
    do {                                                                          \
        const int k0_ = (kt) * 32;                                                \
        gload_lds16(A  + (size_t)(m0 + rA0) * HID_ + k0_ + pA0, &As[bufi][c0*8]); \
        gload_lds16(A  + (size_t)(m0 + rA1) * HID_ + k0_ + pA1, &As[bufi][c1*8]); \
        gload_lds16(Wp + (size_t)rA0 * HID_ + k0_ + pA0, &Ws[bufi][c0*8]);        \
        gload_lds16(Wp + (size_t)rA1 * HID_ + k0_ + pA1, &Ws[bufi][c1*8]);        \
    } while (0)

    int cur = 0;
    STAGEG(0, 0);
    __syncthreads();                              // buf0 staged

    for (int kt = 0; kt < HID_ / 32; ++kt) {
        if (kt + 1 < HID_ / 32) STAGEG(cur ^ 1, kt + 1);   // flies under compute

        bf16x8 a[4], b[4];
#pragma unroll
        for (int mi = 0; mi < 4; mi++)
            a[mi] = *(const bf16x8*)&As[cur][(wr * 64 + mi * 16 + l16) * 32 + quad * 8];
#pragma unroll
        for (int ni = 0; ni < 4; ni++)
            b[ni] = *(const bf16x8*)&Ws[cur][(wc * 64 + ni * 16 + l16) * 32 + quad * 8];
#pragma unroll
        for (int mi = 0; mi < 4; mi++)
#pragma unroll
            for (int ni = 0; ni < 4; ni++)
                acc[mi][ni] = __builtin_amdgcn_mfma_f32_16x16x32_bf16(a[mi], b[ni], acc[mi][ni], 0, 0, 0);

        __syncthreads();                          // next-buf DMA drained; reads done
        cur ^= 1;
    }
#undef STAGEG

    // ---- stash C-tile (bias added, bf16) into LDS -------------------------
#pragma unroll
    for (int mi = 0; mi < 4; mi++) {
        const int row = wr * 64 + mi * 16 + quad * 4;
#pragma unroll
        for (int ni = 0; ni < 4; ni++) {
            const int cl = wc * 64 + ni * 16 + l16;
            const float bv = flg ? ((const float*)bias)[boff + cl]
                                 : bf2f(((const unsigned short*)bias)[boff + cl]);
#pragma unroll
            for (int r = 0; r < 4; r++)
                Ct[row + r][cl] = f2bf(acc[mi][ni][r] + bv);
        }
    }
    __syncthreads();

    const int b = m0 >> 11;               // token block -> batch
    const int s0 = m0 & 2047;

    if (n0 >= 1792) {
        // V tile -> transposed write Vt[b][kv][d][s]
        const int kv = (n0 - 1792) >> 7;
        const int d = tid >> 1, sh = (tid & 1) * 64;
        unsigned short* dst = Vt + (((size_t)b * NKV_ + kv) * HD_ + d) * S_ + s0 + sh;
        for (int j0 = 0; j0 < 64; j0 += 8) {
            unsigned short v[8];
#pragma unroll
            for (int j = 0; j < 8; j++) v[j] = Ct[sh + j0 + j][d];
            uint4 o;
            o.x = v[0] | ((unsigned int)v[1] << 16);
            o.y = v[2] | ((unsigned int)v[3] << 16);
            o.z = v[4] | ((unsigned int)v[5] << 16);
            o.w = v[6] | ((unsigned int)v[7] << 16);
            *(uint4*)(dst + j0) = o;
        }
    } else {
        // Q or K tile -> mrope then row write
        const int rr = tid >> 1, dh = (tid & 1) * 64;   // row, d-half
        const int s = s0 + rr;
        unsigned short* dst; float qsc;
        if (n0 < 1536) {
            dst = Q + (((size_t)b * NH_ + (n0 >> 7)) * S_ + s) * HD_ + dh;
            qsc = 0.1275174313431108f;     // 1/sqrt(128) * log2(e)
        } else {
            const int kv = (n0 - 1536) >> 7;
            dst = K + (((size_t)b * NKV_ + kv) * S_ + s) * HD_ + dh;
            qsc = 1.0f;
        }
        for (int j0 = 0; j0 < 64; j0 += 8) {
            // 8-chunks never cross mrope axis boundaries (16/40 are mult of 8)
            const int axis = (j0 < 16) ? 0 : (j0 < 40 ? 1 : 2);
            const size_t cidx = (((size_t)axis * B_ + b) * S_ + s) * HD_ + dh + j0;
            float cs[8], sn[8];
            if (flg) {
                const float4 ca_ = *(const float4*)((const float*)cosp + cidx);
                const float4 cb_ = *(const float4*)((const float*)cosp + cidx + 4);
                const float4 sa_ = *(const float4*)((const float*)sinp + cidx);
                const float4 sb_ = *(const float4*)((const float*)sinp + cidx + 4);
                cs[0]=ca_.x; cs[1]=ca_.y; cs[2]=ca_.z; cs[3]=ca_.w;
                cs[4]=cb_.x; cs[5]=cb_.y; cs[6]=cb_.z; cs[7]=cb_.w;
                sn[0]=sa_.x; sn[1]=sa_.y; sn[2]=sa_.z; sn[3]=sa_.w;
                sn[4]=sb_.x; sn[5]=sb_.y; sn[6]=sb_.z; sn[7]=sb_.w;
            } else {
                const unsigned short* cp = (const unsigned short*)cosp + cidx;
                const unsigned short* sp = (const unsigned short*)sinp + cidx;
#pragma unroll
                for (int j = 0; j < 8; j++) { cs[j] = bf2f(cp[j]); sn[j] = bf2f(sp[j]); }
            }
            const bf16x8 xc = *(const bf16x8*)&Ct[rr][dh + j0];
            const bf16x8 xp = *(const bf16x8*)&Ct[rr][(dh ^ 64) + j0];
            unsigned short v[8];
#pragma unroll
            for (int j = 0; j < 8; j++) {
                const float x = bf2f((unsigned short)xc[j]);
                const float p = bf2f((unsigned short)xp[j]);
                const float y = (dh == 0) ? (x * cs[j] - p * sn[j])
                                          : (x * cs[j] + p * sn[j]);
                v[j] = f2bf(y * qsc);
            }
            uint4 o;
            o.x = v[0] | ((unsigned int)v[1] << 16);
            o.y = v[2] | ((unsigned int)v[3] << 16);
            o.z = v[4] | ((unsigned int)v[5] << 16);
            o.w = v[6] | ((unsigned int)v[7] << 16);
            *(uint4*)(dst + j0) = o;
        }
    }
}

__global__ __launch_bounds__(256) void gemm_o(
    const unsigned short* __restrict__ A,   // attn_out [4096,1536] bf16
    const unsigned short* __restrict__ W,   // o_w bf16 [1536,1536]
    const int* __restrict__ flag,
    void* __restrict__ C)                   // out [4096,1536] bf16 or f32
{
    __shared__ unsigned short As[2][128 * 32];
    __shared__ unsigned short Ws[2][128 * 32];
    const int tid = threadIdx.x;
    const int w = tid >> 6, lane = tid & 63, quad = lane >> 4, l16 = lane & 15;
    const int wr = w >> 1, wc = w & 1;
    const int n0 = blockIdx.x * 128;
    const int m0 = blockIdx.y * 128;
    const int flg = flag[0];
    const unsigned short* Wp = W + (size_t)n0 * HID_;

    f32x4 acc[4][4];
#pragma unroll
    for (int i = 0; i < 4; i++)
#pragma unroll
        for (int j = 0; j < 4; j++) acc[i][j] = (f32x4)0.0f;

    const int c0 = w * 64, c1 = 256 + w * 64;
    const int ca = c0 + lane, cb = c1 + lane;
    const int rA0 = ca >> 2, pA0 = (ca & 3) * 8;
    const int rA1 = cb >> 2, pA1 = (cb & 3) * 8;

#define STAGEG(bufi, kt)                                                          \
    do {                                                                          \
        const int k0_ = (kt) * 32;                                                \
        gload_lds16(A  + (size_t)(m0 + rA0) * HID_ + k0_ + pA0, &As[bufi][c0*8]); \
        gload_lds16(A  + (size_t)(m0 + rA1) * HID_ + k0_ + pA1, &As[bufi][c1*8]); \
        gload_lds16(Wp + (size_t)rA0 * HID_ + k0_ + pA0, &Ws[bufi][c0*8]);        \
        gload_lds16(Wp + (size_t)rA1 * HID_ + k0_ + pA1, &Ws[bufi][c1*8]);        \
    } while (0)

    int cur = 0;
    STAGEG(0, 0);
    __syncthreads();

    for (int kt = 0; kt < HID_ / 32; ++kt) {
        if (kt + 1 < HID_ / 32) STAGEG(cur ^ 1, kt + 1);

        bf16x8 a[4], b[4];
#pragma unroll
        for (int mi = 0; mi < 4; mi++)
            a[mi] = *(const bf16x8*)&As[cur][(wr * 64 + mi * 16 + l16) * 32 + quad * 8];
#pragma unroll
        for (int ni = 0; ni < 4; ni++)
            b[ni] = *(const bf16x8*)&Ws[cur][(wc * 64 + ni * 16 + l16) * 32 + quad * 8];
#pragma unroll
        for (int mi = 0; mi < 4; mi++)
#pragma unroll
            for (int ni = 0; ni < 4; ni++)
                acc[mi][ni] = __builtin_amdgcn_mfma_f32_16x16x32_bf16(a[mi], b[ni], acc[mi][ni], 0, 0, 0);

        __syncthreads();
        cur ^= 1;
    }
#undef STAGEG

#pragma unroll
    for (int mi = 0; mi < 4; mi++) {
        const int row = m0 + wr * 64 + mi * 16 + quad * 4;
#pragma unroll
        for (int ni = 0; ni < 4; ni++) {
            const int col = n0 + wc * 64 + ni * 16 + l16;
#pragma unroll
            for (int r = 0; r < 4; r++) {
                const size_t off = (size_t)(row + r) * HID_ + col;
                if (flg) ((float*)C)[off] = acc[mi][ni][r];
                else ((unsigned short*)C)[off] = f2bf(acc[mi][ni][r]);
            }
        }
    }
}

// ---------------------------------------------------------------------------
// Flash attention v7: v6 tile structure; grid repacked to 960 blocks.
// Grid (24, 40): y<32 -> heavy qt=16+(y>>1), split-K chunk y&1 (partials);
// y>=32 -> light DIAGONAL PAIR (a, 15-a), a=y-32: two full segments,
// uniform 17 k-tiles, direct output. Queue depth 1.5 -> 1.25 waves.
// ---------------------------------------------------------------------------
__global__ __launch_bounds__(256, 3) void attn_fwd(
    const unsigned short* __restrict__ Q,
    const unsigned short* __restrict__ K,
    const unsigned short* __restrict__ Vt,
    float* __restrict__ Opart0,          // [384][64][128] f32 (CV_HS reuse)
    float* __restrict__ Opart1,          // [384][64][128] f32 (d_out scratch)
    float* __restrict__ mlp,             // [384][2][2][64] f32 (m,l per chunk)
    unsigned short* __restrict__ Aout)   // [4096, 1536]
{
    __shared__ unsigned short Ks2[2][64 * 128];   // linear, swizzled content
    __shared__ unsigned short Vs1[128 * 64];      // linear, swizzled content

    const int tid = threadIdx.x;
    const int w = tid >> 6, lane = tid & 63, quad = lane >> 4, l16 = lane & 15;
    const int bh = blockIdx.x;              // 0..23
    const int y  = blockIdx.y;              // 0..39
    int qt0, qt1s, chunk, nseg; bool split;
    if (y < 32) {                            // heavy tiles, split in two
        split = true; nseg = 1;
        qt0 = 16 + (y >> 1);
        chunk = y & 1;
        qt1s = -1;
    } else {                                 // light diagonal pair
        split = false; chunk = 0; nseg = 2;
        qt0 = y - 32;                        // 0..7
        qt1s = 15 - qt0;                     // 15..8
    }
    const int h  = bh % NH_;
    const int b  = bh / NH_;
    const int kvh = h / GRP_;

    const char* Kg = (const char*)(K  + ((size_t)b * NKV_ + kvh) * S_ * HD_);
    const char* Vg = (const char*)(Vt + ((size_t)b * NKV_ + kvh) * HD_ * S_);

    // Per-lane pre-swizzled source byte offsets for the DMA chunks.
    int offK[4], offV[4];
#pragma unroll
    for (int i = 0; i < 4; i++) {
        const int cK = w * 4 + i;
        const int krow = cK * 4 + (lane >> 4);
        const int kc = (lane & 15) * 16;
        offK[i] = krow * 256 + (kc ^ ((krow & 7) << 4));
        const int cV = w * 4 + i;
        const int vrow = cV * 8 + (lane >> 3);
        const int vc = (lane & 7) * 16;
        offV[i] = vrow * 4096 + (vc ^ ((vrow & 7) << 4));
    }

#define STAGE_K(bufi, tt)                                                      \
    do {                                                                       \
        char* kd_ = (char*)&Ks2[bufi][0];                                      \
        _Pragma("unroll")                                                      \
        for (int i_ = 0; i_ < 4; i_++)                                         \
            gload_lds16b(Kg + (tt) * 16384 + offK[i_],                         \
                         kd_ + (w * 4 + i_) * 1024);                           \
    } while (0)
#define STAGE_V(tt)                                                            \
    do {                                                                       \
        char* vd_ = (char*)&Vs1[0];                                            \
        _Pragma("unroll")                                                      \
        for (int i_ = 0; i_ < 4; i_++)                                         \
            gload_lds16b(Vg + (tt) * 128 + offV[i_],                           \
                         vd_ + (w * 4 + i_) * 1024);                           \
    } while (0)

    const int xorb = (l16 & 7) << 4;     // read-side swizzle (row&7 == l16&7)

#pragma unroll 1
    for (int seg = 0; seg < nseg; ++seg) {
        const int qt = (seg == 0) ? qt0 : qt1s;
        const int q0 = qt * 64;
        int t0, t1;
        if (split) {
            const int half = (qt + 1) >> 1;
            t0 = chunk ? half : 0;
            t1 = chunk ? (qt + 1) : half;
        } else {
            t0 = 0; t1 = qt + 1;
        }

        const unsigned short* Qp = Q + (((size_t)b * NH_ + h) * S_ + q0) * HD_;
        bf16x8 aq[4];
        {
            const unsigned short* qr = Qp + (size_t)(w * 16 + l16) * HD_ + quad * 8;
#pragma unroll
            for (int ks = 0; ks < 4; ks++)
                aq[ks] = *(const bf16x8*)(qr + ks * 32);
        }

        f32x4 Ot[8];                         // O^T fragments: row d, col q=l16
#pragma unroll
        for (int i = 0; i < 8; i++) Ot[i] = (f32x4)0.0f;
        float m_st = -1e30f, l_st = 0.f;     // lane-local (q = l16)
        int cur = 0;

        STAGE_K(0, t0);
        __syncthreads();      // vmcnt(0) drain at barrier -> K[t0] staged

        for (int t = t0; t < t1; t++) {
            const int k0 = t * 64;
            STAGE_V(t);                                // lands at B1
            if (t + 1 < t1) STAGE_K(cur ^ 1, t + 1);   // lands at B1 (early, ok)

            const char* kb_ = (const char*)&Ks2[cur][0];

            // S^T = K * Q^T : rows k (A = K-frag), cols q (B = Q-frag).
            f32x4 Sf[4];
#pragma unroll
            for (int i = 0; i < 4; i++) Sf[i] = (f32x4)0.0f;
            __builtin_amdgcn_s_setprio(1);
#pragma unroll
            for (int ks = 0; ks < 4; ks++) {
#pragma unroll
                for (int ni = 0; ni < 4; ni++) {
                    bf16x8 bk = *(const bf16x8*)(kb_ + (ni * 16 + l16) * 256 +
                                                 ((ks * 64 + quad * 16) ^ xorb));
                    Sf[ni] = __builtin_amdgcn_mfma_f32_16x16x32_bf16(bk, aq[ks], Sf[ni], 0, 0, 0);
                }
            }
            __builtin_amdgcn_s_setprio(0);

            // causal mask only on the diagonal tile
            if (t == qt) {
                const int qq = q0 + w * 16 + l16;
#pragma unroll
                for (int ni = 0; ni < 4; ni++)
#pragma unroll
                    for (int r = 0; r < 4; r++) {
                        const int kk = k0 + ni * 16 + quad * 4 + r;
                        if (kk > qq) Sf[ni][r] = -1e9f;
                    }
            }

            // lane-local online softmax (exp2 domain; log2e folded into Q)
            float mx = Sf[0][0];
#pragma unroll
            for (int ni = 0; ni < 4; ni++)
#pragma unroll
                for (int r = 0; r < 4; r++) mx = fmaxf(mx, Sf[ni][r]);
            mx = fmaxf(mx, __shfl_xor(mx, 16, 64));
            mx = fmaxf(mx, __shfl_xor(mx, 32, 64));
            const float mn = fmaxf(m_st, mx);
            const float alpha = exp2f(m_st - mn);
            m_st = mn;
            float ps = 0.f;
#pragma unroll
            for (int ni = 0; ni < 4; ni++)
#pragma unroll
                for (int r = 0; r < 4; r++) {
                    const float p = exp2f(Sf[ni][r] - mn);
                    Sf[ni][r] = p;
                    ps += p;
                }
            ps += __shfl_xor(ps, 16, 64);
            ps += __shfl_xor(ps, 32, 64);
            l_st = l_st * alpha + ps;
#pragma unroll
            for (int di = 0; di < 8; di++)
#pragma unroll
                for (int r = 0; r < 4; r++) Ot[di][r] *= alpha;

            __syncthreads();   // B1: V[t] (and K[t+1]) landed

            // O^T += V^T * P^T  (A = V^T-frag from LDS, B = P^T from S^T C-frag)
            const char* vb_ = (const char*)&Vs1[0];
            __builtin_amdgcn_s_setprio(1);
#pragma unroll
            for (int ni = 0; ni < 4; ni++) {
                bf16x4 pa;
                pa[0] = (short)f2bf(Sf[ni][0]);
                pa[1] = (short)f2bf(Sf[ni][1]);
                pa[2] = (short)f2bf(Sf[ni][2]);
                pa[3] = (short)f2bf(Sf[ni][3]);
#pragma unroll
                for (int di = 0; di < 8; di++) {
                    bf16x4 va = *(const bf16x4*)(vb_ + (di * 16 + l16) * 128 +
                                                 ((ni * 32 + quad * 8) ^ xorb));
                    Ot[di] = mfma16(va, pa, Ot[di]);
                }
            }
            __builtin_amdgcn_s_setprio(0);

            __syncthreads();   // B2: all Vs reads done before next STAGE_V
            cur ^= 1;
        }

        const int rowl = w * 16 + l16;           // local q-row (0..63)
        if (!split) {
            const float rl = 1.0f / l_st;
            const int qrow = q0 + rowl;
            unsigned short* dst = Aout + ((size_t)b * S_ + qrow) * HID_ + h * HD_;
#pragma unroll
            for (int di = 0; di < 8; di++) {
                ushort4 o;
                o.x = f2bf(Ot[di][0] * rl);
                o.y = f2bf(Ot[di][1] * rl);
                o.z = f2bf(Ot[di][2] * rl);
                o.w = f2bf(Ot[di][3] * rl);
                *(ushort4*)(dst + di * 16 + quad * 4) = o;
            }
        } else {
            const int pair = bh * 16 + (qt - 16);          // 0..383
            float* Ob = (chunk ? Opart1 : Opart0) + (size_t)pair * 8192;
#pragma unroll
            for (int di = 0; di < 8; di++)
                *(f32x4*)&Ob[rowl * 128 + di * 16 + quad * 4] = Ot[di];
            if (quad == 0) {
                mlp[pair * 256 + chunk * 128 + rowl]      = m_st;
                mlp[pair * 256 + chunk * 128 + 64 + rowl] = l_st;
            }
        }
    }
#undef STAGE_K
#undef STAGE_V
}

// ---------------------------------------------------------------------------
// Combine the two split-K partials per heavy q-tile; write bf16 into Aout.
// ---------------------------------------------------------------------------
__global__ __launch_bounds__(256) void attn_combine(
    const float* __restrict__ Opart0, const float* __restrict__ Opart1,
    const float* __restrict__ mlp, unsigned short* __restrict__ Aout)
{
    const int pair = blockIdx.x;             // 0..383
    const int bh = pair >> 4;
    const int qt = 16 + (pair & 15);
    const int h = bh % NH_, b = bh / NH_;
    const int q0 = qt * 64;
    const int row = threadIdx.x >> 2;        // 0..63
    const int dseg = (threadIdx.x & 3) * 32; // 0,32,64,96

    const float m0 = mlp[pair * 256 + row],       l0 = mlp[pair * 256 + 64 + row];
    const float m1 = mlp[pair * 256 + 128 + row], l1 = mlp[pair * 256 + 192 + row];
    const float m = fmaxf(m0, m1);
    const float s0 = exp2f(m0 - m), s1 = exp2f(m1 - m);
    const float rl = 1.0f / (l0 * s0 + l1 * s1);

    const float* O0 = Opart0 + (size_t)pair * 8192 + row * 128 + dseg;
    const float* O1 = Opart1 + (size_t)pair * 8192 + row * 128 + dseg;
    unsigned short* dst = Aout + ((size_t)b * S_ + q0 + row) * HID_ + h * HD_ + dseg;
#pragma unroll
    for (int j = 0; j < 32; j += 4) {
        const float4 a = *(const float4*)(O0 + j);
        const float4 c = *(const float4*)(O1 + j);
        ushort4 o;
        o.x = f2bf((a.x * s0 + c.x * s1) * rl);
        o.y = f2bf((a.y * s0 + c.y * s1) * rl);
        o.z = f2bf((a.z * s0 + c.z * s1) * rl);
        o.w = f2bf((a.w * s0 + c.w * s1) * rl);
        *(ushort4*)(dst + j) = o;
    }
}

extern "C" void kernel_launch(void* const* d_in, const int* in_sizes, int n_in,
                              void* d_out, int out_size, void* d_ws, size_t ws_size,
                              hipStream_t stream) {
    const void* hs   = d_in[0];
    const void* qw   = d_in[1];
    const void* qb   = d_in[2];
    const void* kw   = d_in[3];
    const void* kb   = d_in[4];
    const void* vw   = d_in[5];
    const void* vb   = d_in[6];
    const void* ow   = d_in[7];
    const void* cosp = d_in[8];
    const void* sinp = d_in[9];

    int* flag = (int*)d_ws;                                       // 16 shorts reserved
    unsigned short* conv = (unsigned short*)d_ws + 16;            // CV_TOT = 11796480
    unsigned short* Cqkv = conv + CV_TOT;                         // 8388608 (now Ao only)
    unsigned short* Qb   = Cqkv + (size_t)8388608;                // 6291456
    unsigned short* Kb   = Qb + (size_t)6291456;                  // 1048576
    unsigned short* Vtb  = Kb + (size_t)1048576;                  // 1048576
    unsigned short* Ao   = Cqkv;                                  // attn output
    // Split-K partials — all in memory dead at attn time, zero footprint growth:
    //   chunk0 -> dead CV_HS conv region (384*8192 f32 = 3,145,728 f32 exact)
    //   chunk1 -> d_out scratch (>= 12.58 MB for both output dtypes; consumed
    //             by attn_combine before gemm_o rewrites d_out)
    //   m/l    -> dead qw conv region (98,304 f32 of 2,359,296-short region)
    float* Opart0 = (float*)conv;
    float* Opart1 = (float*)d_out;
    float* mlp    = (float*)(conv + CV_QW);

    detect_dtype<<<1, 64, 0, stream>>>((const unsigned short*)hs, flag);
    convert_inputs<<<(CV_TOT / 8 + 255) / 256, 256, 0, stream>>>(hs, qw, kw, vw, ow, flag, conv);
    gemm_qkv<<<dim3(16, 32), 256, 0, stream>>>(conv + CV_HS, conv, qb, kb, vb,
                                               cosp, sinp, flag, Qb, Kb, Vtb);
    attn_fwd<<<dim3(24, 40), 256, 0, stream>>>(Qb, Kb, Vtb, Opart0, Opart1, mlp, Ao);
    attn_combine<<<dim3(384), 256, 0, stream>>>(Opart0, Opart1, mlp, Ao);
    gemm_o<<<dim3(12, 32), 256, 0, stream>>>(Ao, conv + CV_OW, flag, d_out);
}

// Round 10
// 315.567 us; speedup vs baseline: 1.1151x; 1.0480x over previous
//
#include <hip/hip_runtime.h>

// Problem constants
#define B_    2
#define S_    2048
#define HID_  1536
#define NH_   12
#define NKV_  2
#define HD_   128
#define GRP_  6
#define NQKV_ 2048

// converted-input region layout (element offsets)
#define CV_HS  0
#define CV_QW  6291456
#define CV_KW  8650752
#define CV_VW  9043968
#define CV_OW  9437184
#define CV_TOT 11796480

typedef __attribute__((ext_vector_type(8))) short bf16x8;
typedef __attribute__((ext_vector_type(4))) short bf16x4;
typedef __attribute__((ext_vector_type(4))) float f32x4;

__device__ __forceinline__ float bf2f(unsigned short u) {
    union { unsigned int i; float f; } v; v.i = ((unsigned int)u) << 16; return v.f;
}
__device__ __forceinline__ unsigned short f2bf(float f) {
    union { float f; unsigned int i; } v; v.f = f;
    unsigned int r = v.i + 0x7fffu + ((v.i >> 16) & 1u);  // RNE
    return (unsigned short)(r >> 16);
}

// Inline dtype detection (replaces detect_dtype kernel + flag[0] load).
// bf16 input: even-indexed ushorts are bf16 values with sane exponents.
// f32 input: even-indexed ushorts are low mantissa halves (garbage).
// Must be called with a full wave active (before any divergent return).
__device__ __forceinline__ int detect_flag(const unsigned short* hs) {
    const int i = threadIdx.x & 63;
    const unsigned short u = hs[2 * i];
    const int e = (u >> 7) & 0xFF;
    const bool sane = (e >= 96 && e <= 143);
    return (__popcll(__ballot(sane)) < 32) ? 1 : 0;
}

__device__ __forceinline__ void gload_lds16(const unsigned short* g, unsigned short* l) {
    __builtin_amdgcn_global_load_lds(
        (const __attribute__((address_space(1))) void*)g,
        (__attribute__((address_space(3))) void*)l, 16, 0, 0);
}
__device__ __forceinline__ void gload_lds16b(const char* g, char* l) {
    __builtin_amdgcn_global_load_lds(
        (const __attribute__((address_space(1))) void*)g,
        (__attribute__((address_space(3))) void*)l, 16, 0, 0);
}

// 16x16x16 bf16 MFMA (PV step): builtin name varies across ROCm versions.
#if __has_builtin(__builtin_amdgcn_mfma_f32_16x16x16bf16_1k)
__device__ __forceinline__ f32x4 mfma16(bf16x4 a, bf16x4 b, f32x4 c) {
    return __builtin_amdgcn_mfma_f32_16x16x16bf16_1k(a, b, c, 0, 0, 0);
}
#elif __has_builtin(__builtin_amdgcn_mfma_f32_16x16x16_bf16)
__device__ __forceinline__ f32x4 mfma16(bf16x4 a, bf16x4 b, f32x4 c) {
    return __builtin_amdgcn_mfma_f32_16x16x16_bf16(a, b, c, 0, 0, 0);
}
#else
__device__ __forceinline__ f32x4 mfma16(bf16x4 a, bf16x4 b, f32x4 c) {
    asm volatile("v_mfma_f32_16x16x16_bf16 %0, %1, %2, %0"
                 : "+v"(c) : "v"(a), "v"(b));
    return c;
}
#endif

// 8 elements per thread; all region boundaries are multiples of 8.
__global__ __launch_bounds__(256) void convert_inputs(
    const void* __restrict__ hs, const void* __restrict__ qw,
    const void* __restrict__ kw, const void* __restrict__ vw,
    const void* __restrict__ ow,
    unsigned short* __restrict__ dst)
{
    const int flg = detect_flag((const unsigned short*)hs);
    const size_t idx = ((size_t)blockIdx.x * 256 + threadIdx.x) * 8;
    if (idx >= CV_TOT) return;
    const void* p; size_t j;
    if (idx < CV_QW)      { p = hs; j = idx; }
    else if (idx < CV_KW) { p = qw; j = idx - CV_QW; }
    else if (idx < CV_VW) { p = kw; j = idx - CV_KW; }
    else if (idx < CV_OW) { p = vw; j = idx - CV_VW; }
    else                  { p = ow; j = idx - CV_OW; }
    if (flg) {
        const float* src = (const float*)p + j;
        const float4 f0 = *(const float4*)(src);
        const float4 f1 = *(const float4*)(src + 4);
        uint4 o;
        o.x = (unsigned int)f2bf(f0.x) | ((unsigned int)f2bf(f0.y) << 16);
        o.y = (unsigned int)f2bf(f0.z) | ((unsigned int)f2bf(f0.w) << 16);
        o.z = (unsigned int)f2bf(f1.x) | ((unsigned int)f2bf(f1.y) << 16);
        o.w = (unsigned int)f2bf(f1.z) | ((unsigned int)f2bf(f1.w) << 16);
        *(uint4*)(dst + idx) = o;
    } else {
        *(uint4*)(dst + idx) = *(const uint4*)((const unsigned short*)p + j);
    }
}

// ---------------------------------------------------------------------------
// GEMM QKV + fused mrope/scatter. 1-D grid of 512 blocks with XCD-region
// remap: bid = xcd + 8*local; each XCD owns an 8x8 (col x row) tile region,
// so A row-panels and W col-panels are fetched by 2/4 XCDs instead of 8.
// Epilogue: stash bf16 C-tile in LDS, apply mrope, write Q/K (Q pre-scaled
// by 1/sqrt(128)*log2e) or the V [HD][S] transpose.
// ---------------------------------------------------------------------------
__global__ __launch_bounds__(256) void gemm_qkv(
    const unsigned short* __restrict__ hsorig, // original hs (dtype probe)
    const unsigned short* __restrict__ A,      // bf16 hidden [4096,1536]
    const unsigned short* __restrict__ Wall,   // bf16 region base (qw/kw/vw)
    const void* __restrict__ qb, const void* __restrict__ kb,
    const void* __restrict__ vb,
    const void* __restrict__ cosp, const void* __restrict__ sinp,
    unsigned short* __restrict__ Q,            // [B,NH,S,HD]
    unsigned short* __restrict__ K,            // [B,NKV,S,HD]
    unsigned short* __restrict__ Vt)           // [B,NKV,HD,S]
{
    __shared__ char sm[34816];                           // staging / C-stash union
    unsigned short (*As)[4096] = (unsigned short (*)[4096])sm;            // [2][4096]
    unsigned short (*Ws)[4096] = (unsigned short (*)[4096])(sm + 16384);  // [2][4096]
    unsigned short (*Ct)[136]  = (unsigned short (*)[136])sm;             // [128][136]

    const int flg = detect_flag(hsorig);
    const int tid = threadIdx.x;
    const int w = tid >> 6, lane = tid & 63, quad = lane >> 4, l16 = lane & 15;
    const int wr = w >> 1, wc = w & 1;
    // XCD-region remap: region (xcd) = 8 cols x 8 rows of the 16x32 grid.
    const int bid = blockIdx.x;
    const int xcd = bid & 7, loc = bid >> 3;
    const int n0 = (((xcd & 1) << 3) + (loc & 7)) * 128;
    const int m0 = (((xcd >> 1) << 3) + (loc >> 3)) * 128;

    const unsigned short* Wp; const void* bias; int boff;
    if (n0 < 1536)      { Wp = Wall + CV_QW + (size_t)n0 * HID_;          bias = qb; boff = n0; }
    else if (n0 < 1792) { Wp = Wall + CV_KW + (size_t)(n0 - 1536) * HID_; bias = kb; boff = n0 - 1536; }
    else                { Wp = Wall + CV_VW + (size_t)(n0 - 1792) * HID_; bias = vb; boff = n0 - 1792; }

    f32x4 acc[4][4];
#pragma unroll
    for (int i = 0; i < 4; i++)
#pragma unroll
        for (int j = 0; j < 4; j++) acc[i][j] = (f32x4)0.0f;

    const int c0 = w * 64, c1 = 256 + w * 64;
    const int ca = c0 + lane, cb = c1 + lane;
    const int rA0 = ca >> 2, pA0 = (ca & 3) * 8;
    const int rA1 = cb >> 2, pA1 = (cb & 3) * 8;

#define STAGEG(bufi, kt)                                                          \
    do {                                                                          \
        const int k0_ = (kt) * 32;                                                \
        gload_lds16(A  + (size_t)(m0 + rA0) * HID_ + k0_ + pA0, &As[bufi][c0*8]); \
        gload_lds16(A  + (size_t)(m0 + rA1) * HID_ + k0_ + pA1, &As[bufi][c1*8]); \
        gload_lds16(Wp + (size_t)rA0 * HID_ + k0_ + pA0, &Ws[bufi][c0*8]);        \
        gload_lds16(Wp + (size_t)rA1 * HID_ + k0_ + pA1, &Ws[bufi][c1*8]);        \
    } while (0)

    int cur = 0;
    STAGEG(0, 0);
    __syncthreads();                              // buf0 staged

    for (int kt = 0; kt < HID_ / 32; ++kt) {
        if (kt + 1 < HID_ / 32) STAGEG(cur ^ 1, kt + 1);   // flies under compute

        bf16x8 a[4], b[4];
#pragma unroll
        for (int mi = 0; mi < 4; mi++)
            a[mi] = *(const bf16x8*)&As[cur][(wr * 64 + mi * 16 + l16) * 32 + quad * 8];
#pragma unroll
        for (int ni = 0; ni < 4; ni++)
            b[ni] = *(const bf16x8*)&Ws[cur][(wc * 64 + ni * 16 + l16) * 32 + quad * 8];
#pragma unroll
        for (int mi = 0; mi < 4; mi++)
#pragma unroll
            for (int ni = 0; ni < 4; ni++)
                acc[mi][ni] = __builtin_amdgcn_mfma_f32_16x16x32_bf16(a[mi], b[ni], acc[mi][ni], 0, 0, 0);

        __syncthreads();                          // next-buf DMA drained; reads done
        cur ^= 1;
    }
#undef STAGEG

    // ---- stash C-tile (bias added, bf16) into LDS -------------------------
#pragma unroll
    for (int mi = 0; mi < 4; mi++) {
        const int row = wr * 64 + mi * 16 + quad * 4;
#pragma unroll
        for (int ni = 0; ni < 4; ni++) {
            const int cl = wc * 64 + ni * 16 + l16;
            const float bv = flg ? ((const float*)bias)[boff + cl]
                                 : bf2f(((const unsigned short*)bias)[boff + cl]);
#pragma unroll
            for (int r = 0; r < 4; r++)
                Ct[row + r][cl] = f2bf(acc[mi][ni][r] + bv);
        }
    }
    __syncthreads();

    const int b = m0 >> 11;               // token block -> batch
    const int s0 = m0 & 2047;

    if (n0 >= 1792) {
        // V tile -> transposed write Vt[b][kv][d][s]
        const int kv = (n0 - 1792) >> 7;
        const int d = tid >> 1, sh = (tid & 1) * 64;
        unsigned short* dst = Vt + (((size_t)b * NKV_ + kv) * HD_ + d) * S_ + s0 + sh;
        for (int j0 = 0; j0 < 64; j0 += 8) {
            unsigned short v[8];
#pragma unroll
            for (int j = 0; j < 8; j++) v[j] = Ct[sh + j0 + j][d];
            uint4 o;
            o.x = v[0] | ((unsigned int)v[1] << 16);
            o.y = v[2] | ((unsigned int)v[3] << 16);
            o.z = v[4] | ((unsigned int)v[5] << 16);
            o.w = v[6] | ((unsigned int)v[7] << 16);
            *(uint4*)(dst + j0) = o;
        }
    } else {
        // Q or K tile -> mrope then row write
        const int rr = tid >> 1, dh = (tid & 1) * 64;   // row, d-half
        const int s = s0 + rr;
        unsigned short* dst; float qsc;
        if (n0 < 1536) {
            dst = Q + (((size_t)b * NH_ + (n0 >> 7)) * S_ + s) * HD_ + dh;
            qsc = 0.1275174313431108f;     // 1/sqrt(128) * log2(e)
        } else {
            const int kv = (n0 - 1536) >> 7;
            dst = K + (((size_t)b * NKV_ + kv) * S_ + s) * HD_ + dh;
            qsc = 1.0f;
        }
        for (int j0 = 0; j0 < 64; j0 += 8) {
            // 8-chunks never cross mrope axis boundaries (16/40 are mult of 8)
            const int axis = (j0 < 16) ? 0 : (j0 < 40 ? 1 : 2);
            const size_t cidx = (((size_t)axis * B_ + b) * S_ + s) * HD_ + dh + j0;
            float cs[8], sn[8];
            if (flg) {
                const float4 ca_ = *(const float4*)((const float*)cosp + cidx);
                const float4 cb_ = *(const float4*)((const float*)cosp + cidx + 4);
                const float4 sa_ = *(const float4*)((const float*)sinp + cidx);
                const float4 sb_ = *(const float4*)((const float*)sinp + cidx + 4);
                cs[0]=ca_.x; cs[1]=ca_.y; cs[2]=ca_.z; cs[3]=ca_.w;
                cs[4]=cb_.x; cs[5]=cb_.y; cs[6]=cb_.z; cs[7]=cb_.w;
                sn[0]=sa_.x; sn[1]=sa_.y; sn[2]=sa_.z; sn[3]=sa_.w;
                sn[4]=sb_.x; sn[5]=sb_.y; sn[6]=sb_.z; sn[7]=sb_.w;
            } else {
                const unsigned short* cp = (const unsigned short*)cosp + cidx;
                const unsigned short* sp = (const unsigned short*)sinp + cidx;
#pragma unroll
                for (int j = 0; j < 8; j++) { cs[j] = bf2f(cp[j]); sn[j] = bf2f(sp[j]); }
            }
            const bf16x8 xc = *(const bf16x8*)&Ct[rr][dh + j0];
            const bf16x8 xp = *(const bf16x8*)&Ct[rr][(dh ^ 64) + j0];
            unsigned short v[8];
#pragma unroll
            for (int j = 0; j < 8; j++) {
                const float x = bf2f((unsigned short)xc[j]);
                const float p = bf2f((unsigned short)xp[j]);
                const float y = (dh == 0) ? (x * cs[j] - p * sn[j])
                                          : (x * cs[j] + p * sn[j]);
                v[j] = f2bf(y * qsc);
            }
            uint4 o;
            o.x = v[0] | ((unsigned int)v[1] << 16);
            o.y = v[2] | ((unsigned int)v[3] << 16);
            o.z = v[4] | ((unsigned int)v[5] << 16);
            o.w = v[6] | ((unsigned int)v[7] << 16);
            *(uint4*)(dst + j0) = o;
        }
    }
}

// 1-D grid 384 blocks; XCD-region remap: each XCD owns 12 cols x 4 rows.
__global__ __launch_bounds__(256) void gemm_o(
    const unsigned short* __restrict__ hsorig,
    const unsigned short* __restrict__ A,   // attn_out [4096,1536] bf16
    const unsigned short* __restrict__ W,   // o_w bf16 [1536,1536]
    void* __restrict__ C)                   // out [4096,1536] bf16 or f32
{
    __shared__ unsigned short As[2][128 * 32];
    __shared__ unsigned short Ws[2][128 * 32];
    const int flg = detect_flag(hsorig);
    const int tid = threadIdx.x;
    const int w = tid >> 6, lane = tid & 63, quad = lane >> 4, l16 = lane & 15;
    const int wr = w >> 1, wc = w & 1;
    const int bid = blockIdx.x;
    const int xcd = bid & 7, loc = bid >> 3;      // loc in [0,48)
    const int n0 = (loc % 12) * 128;
    const int m0 = (xcd * 4 + loc / 12) * 128;
    const unsigned short* Wp = W + (size_t)n0 * HID_;

    f32x4 acc[4][4];
#pragma unroll
    for (int i = 0; i < 4; i++)
#pragma unroll
        for (int j = 0; j < 4; j++) acc[i][j] = (f32x4)0.0f;

    const int c0 = w * 64, c1 = 256 + w * 64;
    const int ca = c0 + lane, cb = c1 + lane;
    const int rA0 = ca >> 2, pA0 = (ca & 3) * 8;
    const int rA1 = cb >> 2, pA1 = (cb & 3) * 8;

#define STAGEG(bufi, kt)                                                          \
    do {                                                                          \
        const int k0_ = (kt) * 32;                                                \
        gload_lds16(A  + (size_t)(m0 + rA0) * HID_ + k0_ + pA0, &As[bufi][c0*8]); \
        gload_lds16(A  + (size_t)(m0 + rA1) * HID_ + k0_ + pA1, &As[bufi][c1*8]); \
        gload_lds16(Wp + (size_t)rA0 * HID_ + k0_ + pA0, &Ws[bufi][c0*8]);        \
        gload_lds16(Wp + (size_t)rA1 * HID_ + k0_ + pA1, &Ws[bufi][c1*8]);        \
    } while (0)

    int cur = 0;
    STAGEG(0, 0);
    __syncthreads();

    for (int kt = 0; kt < HID_ / 32; ++kt) {
        if (kt + 1 < HID_ / 32) STAGEG(cur ^ 1, kt + 1);

        bf16x8 a[4], b[4];
#pragma unroll
        for (int mi = 0; mi < 4; mi++)
            a[mi] = *(const bf16x8*)&As[cur][(wr * 64 + mi * 16 + l16) * 32 + quad * 8];
#pragma unroll
        for (int ni = 0; ni < 4; ni++)
            b[ni] = *(const bf16x8*)&Ws[cur][(wc * 64 + ni * 16 + l16) * 32 + quad * 8];
#pragma unroll
        for (int mi = 0; mi < 4; mi++)
#pragma unroll
            for (int ni = 0; ni < 4; ni++)
                acc[mi][ni] = __builtin_amdgcn_mfma_f32_16x16x32_bf16(a[mi], b[ni], acc[mi][ni], 0, 0, 0);

        __syncthreads();
        cur ^= 1;
    }
#undef STAGEG

#pragma unroll
    for (int mi = 0; mi < 4; mi++) {
        const int row = m0 + wr * 64 + mi * 16 + quad * 4;
#pragma unroll
        for (int ni = 0; ni < 4; ni++) {
            const int col = n0 + wc * 64 + ni * 16 + l16;
#pragma unroll
            for (int r = 0; r < 4; r++) {
                const size_t off = (size_t)(row + r) * HID_ + col;
                if (flg) ((float*)C)[off] = acc[mi][ni][r];
                else ((unsigned short*)C)[off] = f2bf(acc[mi][ni][r]);
            }
        }
    }
}

// ---------------------------------------------------------------------------
// Flash attention v6 (round-8 verified, 69.9 µs): v4 tile structure + SPLIT-K
// on heavy q-tiles. Grid (24, 48): y<32 -> qt = 16+(y>>1), chunk y&1 (f32
// partial O/m/l); y>=32 -> qt = 47-y, single chunk, direct output.
// ---------------------------------------------------------------------------
__global__ __launch_bounds__(256, 3) void attn_fwd(
    const unsigned short* __restrict__ Q,
    const unsigned short* __restrict__ K,
    const unsigned short* __restrict__ Vt,
    float* __restrict__ Opart0,          // [384][64][128] f32 (CV_HS reuse)
    float* __restrict__ Opart1,          // [384][64][128] f32 (d_out scratch)
    float* __restrict__ mlp,             // [384][2][2][64] f32 (m,l per chunk)
    unsigned short* __restrict__ Aout)   // [4096, 1536]
{
    __shared__ unsigned short Ks2[2][64 * 128];   // linear, swizzled content
    __shared__ unsigned short Vs1[128 * 64];      // linear, swizzled content

    const int tid = threadIdx.x;
    const int w = tid >> 6, lane = tid & 63, quad = lane >> 4, l16 = lane & 15;
    const int bh = blockIdx.x;              // 0..23
    const int y  = blockIdx.y;              // 0..47
    int qt, t0, t1, chunk; bool split;
    if (y < 32) {                            // heavy tiles, split in two
        split = true;
        qt = 16 + (y >> 1);
        chunk = y & 1;
        const int half = (qt + 1) >> 1;
        t0 = chunk ? half : 0;
        t1 = chunk ? (qt + 1) : half;
    } else {                                 // light tiles, single chunk
        split = false; chunk = 0;
        qt = 47 - y;
        t0 = 0; t1 = qt + 1;
    }
    const int h  = bh % NH_;
    const int b  = bh / NH_;
    const int kvh = h / GRP_;
    const int q0 = qt * 64;

    const unsigned short* Qp = Q  + (((size_t)b * NH_ + h) * S_ + q0) * HD_;
    const char* Kg = (const char*)(K  + ((size_t)b * NKV_ + kvh) * S_ * HD_);
    const char* Vg = (const char*)(Vt + ((size_t)b * NKV_ + kvh) * HD_ * S_);

    // Q fragments in registers: row q = l16, k-chunk quad*8 (B-operand of QK^T)
    bf16x8 aq[4];
    {
        const unsigned short* qr = Qp + (size_t)(w * 16 + l16) * HD_ + quad * 8;
#pragma unroll
        for (int ks = 0; ks < 4; ks++)
            aq[ks] = *(const bf16x8*)(qr + ks * 32);
    }

    // Per-lane pre-swizzled source byte offsets for the DMA chunks.
    int offK[4], offV[4];
#pragma unroll
    for (int i = 0; i < 4; i++) {
        const int cK = w * 4 + i;
        const int krow = cK * 4 + (lane >> 4);
        const int kc = (lane & 15) * 16;
        offK[i] = krow * 256 + (kc ^ ((krow & 7) << 4));
        const int cV = w * 4 + i;
        const int vrow = cV * 8 + (lane >> 3);
        const int vc = (lane & 7) * 16;
        offV[i] = vrow * 4096 + (vc ^ ((vrow & 7) << 4));
    }

#define STAGE_K(bufi, tt)                                                      \
    do {                                                                       \
        char* kd_ = (char*)&Ks2[bufi][0];                                      \
        _Pragma("unroll")                                                      \
        for (int i_ = 0; i_ < 4; i_++)                                         \
            gload_lds16b(Kg + (tt) * 16384 + offK[i_],                         \
                         kd_ + (w * 4 + i_) * 1024);                           \
    } while (0)
#define STAGE_V(tt)                                                            \
    do {                                                                       \
        char* vd_ = (char*)&Vs1[0];                                            \
        _Pragma("unroll")                                                      \
        for (int i_ = 0; i_ < 4; i_++)                                         \
            gload_lds16b(Vg + (tt) * 128 + offV[i_],                           \
                         vd_ + (w * 4 + i_) * 1024);                           \
    } while (0)

    f32x4 Ot[8];                         // O^T fragments: row d, col q=l16
#pragma unroll
    for (int i = 0; i < 8; i++) Ot[i] = (f32x4)0.0f;
    float m_st = -1e30f, l_st = 0.f;     // lane-local (q = l16)

    const int xorb = (l16 & 7) << 4;     // read-side swizzle (row&7 == l16&7)
    int cur = 0;

    STAGE_K(0, t0);
    __syncthreads();      // vmcnt(0) drain at barrier -> K[t0] staged

    for (int t = t0; t < t1; t++) {
        const int k0 = t * 64;
        STAGE_V(t);                                // lands at B1
        if (t + 1 < t1) STAGE_K(cur ^ 1, t + 1);   // lands at B1 (early, ok)

        const char* kb_ = (const char*)&Ks2[cur][0];

        // S^T = K * Q^T : rows k (A = K-frag), cols q (B = Q-frag).
        f32x4 Sf[4];
#pragma unroll
        for (int i = 0; i < 4; i++) Sf[i] = (f32x4)0.0f;
        __builtin_amdgcn_s_setprio(1);
#pragma unroll
        for (int ks = 0; ks < 4; ks++) {
#pragma unroll
            for (int ni = 0; ni < 4; ni++) {
                bf16x8 bk = *(const bf16x8*)(kb_ + (ni * 16 + l16) * 256 +
                                             ((ks * 64 + quad * 16) ^ xorb));
                Sf[ni] = __builtin_amdgcn_mfma_f32_16x16x32_bf16(bk, aq[ks], Sf[ni], 0, 0, 0);
            }
        }
        __builtin_amdgcn_s_setprio(0);

        // causal mask only on the diagonal tile (t == qt; never in chunk 0)
        if (t == qt) {
            const int qq = q0 + w * 16 + l16;
#pragma unroll
            for (int ni = 0; ni < 4; ni++)
#pragma unroll
                for (int r = 0; r < 4; r++) {
                    const int kk = k0 + ni * 16 + quad * 4 + r;
                    if (kk > qq) Sf[ni][r] = -1e9f;
                }
        }

        // lane-local online softmax (exp2 domain; log2e folded into Q)
        float mx = Sf[0][0];
#pragma unroll
        for (int ni = 0; ni < 4; ni++)
#pragma unroll
            for (int r = 0; r < 4; r++) mx = fmaxf(mx, Sf[ni][r]);
        mx = fmaxf(mx, __shfl_xor(mx, 16, 64));
        mx = fmaxf(mx, __shfl_xor(mx, 32, 64));
        const float mn = fmaxf(m_st, mx);
        const float alpha = exp2f(m_st - mn);
        m_st = mn;
        float ps = 0.f;
#pragma unroll
        for (int ni = 0; ni < 4; ni++)
#pragma unroll
            for (int r = 0; r < 4; r++) {
                const float p = exp2f(Sf[ni][r] - mn);
                Sf[ni][r] = p;
                ps += p;
            }
        ps += __shfl_xor(ps, 16, 64);
        ps += __shfl_xor(ps, 32, 64);
        l_st = l_st * alpha + ps;
#pragma unroll
        for (int di = 0; di < 8; di++)
#pragma unroll
            for (int r = 0; r < 4; r++) Ot[di][r] *= alpha;

        __syncthreads();   // B1: V[t] (and K[t+1]) landed

        // O^T += V^T * P^T  (A = V^T-frag from LDS, B = P^T from S^T C-frag)
        const char* vb_ = (const char*)&Vs1[0];
        __builtin_amdgcn_s_setprio(1);
#pragma unroll
        for (int ni = 0; ni < 4; ni++) {
            bf16x4 pa;
            pa[0] = (short)f2bf(Sf[ni][0]);
            pa[1] = (short)f2bf(Sf[ni][1]);
            pa[2] = (short)f2bf(Sf[ni][2]);
            pa[3] = (short)f2bf(Sf[ni][3]);
#pragma unroll
            for (int di = 0; di < 8; di++) {
                bf16x4 va = *(const bf16x4*)(vb_ + (di * 16 + l16) * 128 +
                                             ((ni * 32 + quad * 8) ^ xorb));
                Ot[di] = mfma16(va, pa, Ot[di]);
            }
        }
        __builtin_amdgcn_s_setprio(0);

        __syncthreads();   // B2: all Vs reads done before next STAGE_V
        cur ^= 1;
    }
#undef STAGE_K
#undef STAGE_V

    const int rowl = w * 16 + l16;           // local q-row (0..63)
    if (!split) {
        const float rl = 1.0f / l_st;
        const int qrow = q0 + rowl;
        unsigned short* dst = Aout + ((size_t)b * S_ + qrow) * HID_ + h * HD_;
#pragma unroll
        for (int di = 0; di < 8; di++) {
            ushort4 o;
            o.x = f2bf(Ot[di][0] * rl);
            o.y = f2bf(Ot[di][1] * rl);
            o.z = f2bf(Ot[di][2] * rl);
            o.w = f2bf(Ot[di][3] * rl);
            *(ushort4*)(dst + di * 16 + quad * 4) = o;
        }
    } else {
        const int pair = bh * 16 + (qt - 16);          // 0..383
        float* Ob = (chunk ? Opart1 : Opart0) + (size_t)pair * 8192;
#pragma unroll
        for (int di = 0; di < 8; di++)
            *(f32x4*)&Ob[rowl * 128 + di * 16 + quad * 4] = Ot[di];
        if (quad == 0) {
            mlp[pair * 256 + chunk * 128 + rowl]      = m_st;
            mlp[pair * 256 + chunk * 128 + 64 + rowl] = l_st;
        }
    }
}

// ---------------------------------------------------------------------------
// Combine the two split-K partials per heavy q-tile; write bf16 into Aout.
// ---------------------------------------------------------------------------
__global__ __launch_bounds__(256) void attn_combine(
    const float* __restrict__ Opart0, const float* __restrict__ Opart1,
    const float* __restrict__ mlp, unsigned short* __restrict__ Aout)
{
    const int pair = blockIdx.x;             // 0..383
    const int bh = pair >> 4;
    const int qt = 16 + (pair & 15);
    const int h = bh % NH_, b = bh / NH_;
    const int q0 = qt * 64;
    const int row = threadIdx.x >> 2;        // 0..63
    const int dseg = (threadIdx.x & 3) * 32; // 0,32,64,96

    const float m0 = mlp[pair * 256 + row],       l0 = mlp[pair * 256 + 64 + row];
    const float m1 = mlp[pair * 256 + 128 + row], l1 = mlp[pair * 256 + 192 + row];
    const float m = fmaxf(m0, m1);
    const float s0 = exp2f(m0 - m), s1 = exp2f(m1 - m);
    const float rl = 1.0f / (l0 * s0 + l1 * s1);

    const float* O0 = Opart0 + (size_t)pair * 8192 + row * 128 + dseg;
    const float* O1 = Opart1 + (size_t)pair * 8192 + row * 128 + dseg;
    unsigned short* dst = Aout + ((size_t)b * S_ + q0 + row) * HID_ + h * HD_ + dseg;
#pragma unroll
    for (int j = 0; j < 32; j += 4) {
        const float4 a = *(const float4*)(O0 + j);
        const float4 c = *(const float4*)(O1 + j);
        ushort4 o;
        o.x = f2bf((a.x * s0 + c.x * s1) * rl);
        o.y = f2bf((a.y * s0 + c.y * s1) * rl);
        o.z = f2bf((a.z * s0 + c.z * s1) * rl);
        o.w = f2bf((a.w * s0 + c.w * s1) * rl);
        *(ushort4*)(dst + j) = o;
    }
}

extern "C" void kernel_launch(void* const* d_in, const int* in_sizes, int n_in,
                              void* d_out, int out_size, void* d_ws, size_t ws_size,
                              hipStream_t stream) {
    const void* hs   = d_in[0];
    const void* qw   = d_in[1];
    const void* qb   = d_in[2];
    const void* kw   = d_in[3];
    const void* kb   = d_in[4];
    const void* vw   = d_in[5];
    const void* vb   = d_in[6];
    const void* ow   = d_in[7];
    const void* cosp = d_in[8];
    const void* sinp = d_in[9];

    unsigned short* conv = (unsigned short*)d_ws + 16;            // CV_TOT = 11796480
    unsigned short* Cqkv = conv + CV_TOT;                         // 8388608 (Ao)
    unsigned short* Qb   = Cqkv + (size_t)8388608;                // 6291456
    unsigned short* Kb   = Qb + (size_t)6291456;                  // 1048576
    unsigned short* Vtb  = Kb + (size_t)1048576;                  // 1048576
    unsigned short* Ao   = Cqkv;                                  // attn output
    // Split-K partials — all in memory dead at attn time, zero footprint growth:
    //   chunk0 -> dead CV_HS conv region (384*8192 f32 = 3,145,728 f32 exact)
    //   chunk1 -> d_out scratch (>= 12.58 MB for both output dtypes; consumed
    //             by attn_combine before gemm_o rewrites d_out)
    //   m/l    -> dead qw conv region (98,304 f32 of 2,359,296-short region)
    float* Opart0 = (float*)conv;
    float* Opart1 = (float*)d_out;
    float* mlp    = (float*)(conv + CV_QW);

    convert_inputs<<<(CV_TOT / 8 + 255) / 256, 256, 0, stream>>>(hs, qw, kw, vw, ow, conv);
    gemm_qkv<<<dim3(512), 256, 0, stream>>>((const unsigned short*)hs,
                                            conv + CV_HS, conv, qb, kb, vb,
                                            cosp, sinp, Qb, Kb, Vtb);
    attn_fwd<<<dim3(24, 48), 256, 0, stream>>>(Qb, Kb, Vtb, Opart0, Opart1, mlp, Ao);
    attn_combine<<<dim3(384), 256, 0, stream>>>(Opart0, Opart1, mlp, Ao);
    gemm_o<<<dim3(384), 256, 0, stream>>>((const unsigned short*)hs,
                                          Ao, conv + CV_OW, d_out);
}

// Round 12
// 307.382 us; speedup vs baseline: 1.1448x; 1.0266x over previous
//
#include <hip/hip_runtime.h>

// Problem constants
#define B_    2
#define S_    2048
#define HID_  1536
#define NH_   12
#define NKV_  2
#define HD_   128
#define GRP_  6
#define NQKV_ 2048

// converted-input region layout (element offsets)
#define CV_HS  0
#define CV_QW  6291456
#define CV_KW  8650752
#define CV_VW  9043968
#define CV_OW  9437184
#define CV_TOT 11796480

typedef __attribute__((ext_vector_type(8))) short bf16x8;
typedef __attribute__((ext_vector_type(4))) short bf16x4;
typedef __attribute__((ext_vector_type(4))) float f32x4;

// T4 counted waits. Each STAGEG = 4 global_load_lds per wave, so
// "wait for the previous stage, leave the newest in flight" = vmcnt(4).
#define VM4() asm volatile("s_waitcnt vmcnt(4)" ::: "memory")
#define VM0() asm volatile("s_waitcnt vmcnt(0)" ::: "memory")
#define RBAR() __builtin_amdgcn_s_barrier()

__device__ __forceinline__ float bf2f(unsigned short u) {
    union { unsigned int i; float f; } v; v.i = ((unsigned int)u) << 16; return v.f;
}
__device__ __forceinline__ unsigned short f2bf(float f) {
    union { float f; unsigned int i; } v; v.f = f;
    unsigned int r = v.i + 0x7fffu + ((v.i >> 16) & 1u);  // RNE
    return (unsigned short)(r >> 16);
}

// Inline dtype detection. flag 0 = bf16, 1 = f32.
// Must run with a full wave active (before any divergent return).
__device__ __forceinline__ int detect_flag(const unsigned short* hs) {
    const int i = threadIdx.x & 63;
    const unsigned short u = hs[2 * i];
    const int e = (u >> 7) & 0xFF;
    const bool sane = (e >= 96 && e <= 143);
    return (__popcll(__ballot(sane)) < 32) ? 1 : 0;
}

__device__ __forceinline__ void gload_lds16(const unsigned short* g, unsigned short* l) {
    __builtin_amdgcn_global_load_lds(
        (const __attribute__((address_space(1))) void*)g,
        (__attribute__((address_space(3))) void*)l, 16, 0, 0);
}
__device__ __forceinline__ void gload_lds16b(const char* g, char* l) {
    __builtin_amdgcn_global_load_lds(
        (const __attribute__((address_space(1))) void*)g,
        (__attribute__((address_space(3))) void*)l, 16, 0, 0);
}

// 16x16x16 bf16 MFMA (PV step): builtin name varies across ROCm versions.
#if __has_builtin(__builtin_amdgcn_mfma_f32_16x16x16bf16_1k)
__device__ __forceinline__ f32x4 mfma16(bf16x4 a, bf16x4 b, f32x4 c) {
    return __builtin_amdgcn_mfma_f32_16x16x16bf16_1k(a, b, c, 0, 0, 0);
}
#elif __has_builtin(__builtin_amdgcn_mfma_f32_16x16x16_bf16)
__device__ __forceinline__ f32x4 mfma16(bf16x4 a, bf16x4 b, f32x4 c) {
    return __builtin_amdgcn_mfma_f32_16x16x16_bf16(a, b, c, 0, 0, 0);
}
#else
__device__ __forceinline__ f32x4 mfma16(bf16x4 a, bf16x4 b, f32x4 c) {
    asm volatile("v_mfma_f32_16x16x16_bf16 %0, %1, %2, %0"
                 : "+v"(c) : "v"(a), "v"(b));
    return c;
}
#endif

// 8 elements per thread; all region boundaries are multiples of 8.
__global__ __launch_bounds__(256) void convert_inputs(
    const void* __restrict__ hs, const void* __restrict__ qw,
    const void* __restrict__ kw, const void* __restrict__ vw,
    const void* __restrict__ ow,
    unsigned short* __restrict__ dst)
{
    const int flg = detect_flag((const unsigned short*)hs);
    const size_t idx = ((size_t)blockIdx.x * 256 + threadIdx.x) * 8;
    if (idx >= CV_TOT) return;
    const void* p; size_t j;
    if (idx < CV_QW)      { p = hs; j = idx; }
    else if (idx < CV_KW) { p = qw; j = idx - CV_QW; }
    else if (idx < CV_VW) { p = kw; j = idx - CV_KW; }
    else if (idx < CV_OW) { p = vw; j = idx - CV_VW; }
    else                  { p = ow; j = idx - CV_OW; }
    if (flg) {
        const float* src = (const float*)p + j;
        const float4 f0 = *(const float4*)(src);
        const float4 f1 = *(const float4*)(src + 4);
        uint4 o;
        o.x = (unsigned int)f2bf(f0.x) | ((unsigned int)f2bf(f0.y) << 16);
        o.y = (unsigned int)f2bf(f0.z) | ((unsigned int)f2bf(f0.w) << 16);
        o.z = (unsigned int)f2bf(f1.x) | ((unsigned int)f2bf(f1.y) << 16);
        o.w = (unsigned int)f2bf(f1.z) | ((unsigned int)f2bf(f1.w) << 16);
        *(uint4*)(dst + idx) = o;
    } else {
        *(uint4*)(dst + idx) = *(const uint4*)((const unsigned short*)p + j);
    }
}

// ---------------------------------------------------------------------------
// GEMM QKV + fused mrope/scatter. 1-D grid of 512 blocks with XCD-region
// remap. v12: 3-buffer LDS + counted vmcnt(4) (T4): the end-of-iter wait
// retires only the PREVIOUS stage's 4 loads (a full iteration in flight)
// and leaves this iteration's 4-load prefetch flying across the raw
// s_barrier. No vmcnt(0) drain in the steady-state loop.
// ---------------------------------------------------------------------------
__global__ __launch_bounds__(256) void gemm_qkv(
    const unsigned short* __restrict__ hsorig, // original hs (dtype probe)
    const unsigned short* __restrict__ A,      // bf16 hidden [4096,1536]
    const unsigned short* __restrict__ Wall,   // bf16 region base (qw/kw/vw)
    const void* __restrict__ qb, const void* __restrict__ kb,
    const void* __restrict__ vb,
    const void* __restrict__ cosp, const void* __restrict__ sinp,
    unsigned short* __restrict__ Q,            // [B,NH,S,HD]
    unsigned short* __restrict__ K,            // [B,NKV,S,HD]
    unsigned short* __restrict__ Vt)           // [B,NKV,HD,S]
{
    __shared__ char sm[49152];                           // 3-buf staging / C-stash union
    unsigned short (*As)[4096] = (unsigned short (*)[4096])sm;            // [3][4096]
    unsigned short (*Ws)[4096] = (unsigned short (*)[4096])(sm + 24576);  // [3][4096]
    unsigned short (*Ct)[136]  = (unsigned short (*)[136])sm;             // [128][136]

    const int flg = detect_flag(hsorig);
    const int tid = threadIdx.x;
    const int w = tid >> 6, lane = tid & 63, quad = lane >> 4, l16 = lane & 15;
    const int wr = w >> 1, wc = w & 1;
    // XCD-region remap: region (xcd) = 8 cols x 8 rows of the 16x32 grid.
    const int bid = blockIdx.x;
    const int xcd = bid & 7, loc = bid >> 3;
    const int n0 = (((xcd & 1) << 3) + (loc & 7)) * 128;
    const int m0 = (((xcd >> 1) << 3) + (loc >> 3)) * 128;

    const unsigned short* Wp; const void* bias; int boff;
    if (n0 < 1536)      { Wp = Wall + CV_QW + (size_t)n0 * HID_;          bias = qb; boff = n0; }
    else if (n0 < 1792) { Wp = Wall + CV_KW + (size_t)(n0 - 1536) * HID_; bias = kb; boff = n0 - 1536; }
    else                { Wp = Wall + CV_VW + (size_t)(n0 - 1792) * HID_; bias = vb; boff = n0 - 1792; }

    f32x4 acc[4][4];
#pragma unroll
    for (int i = 0; i < 4; i++)
#pragma unroll
        for (int j = 0; j < 4; j++) acc[i][j] = (f32x4)0.0f;

    const int c0 = w * 64, c1 = 256 + w * 64;
    const int ca = c0 + lane, cb = c1 + lane;
    const int rA0 = ca >> 2, pA0 = (ca & 3) * 8;
    const int rA1 = cb >> 2, pA1 = (cb & 3) * 8;

#define STAGEG(bufi, kt)                                                          \
    do {                                                                          \
        const int k0_ = (kt) * 32;                                                \
        gload_lds16(A  + (size_t)(m0 + rA0) * HID_ + k0_ + pA0, &As[bufi][c0*8]); \
        gload_lds16(A  + (size_t)(m0 + rA1) * HID_ + k0_ + pA1, &As[bufi][c1*8]); \
        gload_lds16(Wp + (size_t)rA0 * HID_ + k0_ + pA0, &Ws[bufi][c0*8]);        \
        gload_lds16(Wp + (size_t)rA1 * HID_ + k0_ + pA1, &Ws[bufi][c1*8]);        \
    } while (0)

    STAGEG(0, 0);
    STAGEG(1, 1);
    VM4();                                        // buf0 landed; buf1 in flight
    RBAR();

    int cur = 0;
    for (int kt = 0; kt < HID_ / 32; ++kt) {
        if (kt + 2 < HID_ / 32)
            STAGEG((cur + 2 >= 3 ? cur - 1 : cur + 2), kt + 2);  // 2-deep prefetch

        bf16x8 a[4], b[4];
#pragma unroll
        for (int mi = 0; mi < 4; mi++)
            a[mi] = *(const bf16x8*)&As[cur][(wr * 64 + mi * 16 + l16) * 32 + quad * 8];
#pragma unroll
        for (int ni = 0; ni < 4; ni++)
            b[ni] = *(const bf16x8*)&Ws[cur][(wc * 64 + ni * 16 + l16) * 32 + quad * 8];
#pragma unroll
        for (int mi = 0; mi < 4; mi++)
#pragma unroll
            for (int ni = 0; ni < 4; ni++)
                acc[mi][ni] = __builtin_amdgcn_mfma_f32_16x16x32_bf16(a[mi], b[ni], acc[mi][ni], 0, 0, 0);

        if (kt + 2 < HID_ / 32) { VM4(); } else { VM0(); }   // retire kt+1 only
        RBAR();
        cur = (cur + 1 == 3) ? 0 : cur + 1;
    }
#undef STAGEG

    // ---- stash C-tile (bias added, bf16) into LDS -------------------------
#pragma unroll
    for (int mi = 0; mi < 4; mi++) {
        const int row = wr * 64 + mi * 16 + quad * 4;
#pragma unroll
        for (int ni = 0; ni < 4; ni++) {
            const int cl = wc * 64 + ni * 16 + l16;
            const float bv = flg ? ((const float*)bias)[boff + cl]
                                 : bf2f(((const unsigned short*)bias)[boff + cl]);
#pragma unroll
            for (int r = 0; r < 4; r++)
                Ct[row + r][cl] = f2bf(acc[mi][ni][r] + bv);
        }
    }
    __syncthreads();

    const int b = m0 >> 11;               // token block -> batch
    const int s0 = m0 & 2047;

    if (n0 >= 1792) {
        // V tile -> transposed write Vt[b][kv][d][s]
        const int kv = (n0 - 1792) >> 7;
        const int d = tid >> 1, sh = (tid & 1) * 64;
        unsigned short* dst = Vt + (((size_t)b * NKV_ + kv) * HD_ + d) * S_ + s0 + sh;
        for (int j0 = 0; j0 < 64; j0 += 8) {
            unsigned short v[8];
#pragma unroll
            for (int j = 0; j < 8; j++) v[j] = Ct[sh + j0 + j][d];
            uint4 o;
            o.x = v[0] | ((unsigned int)v[1] << 16);
            o.y = v[2] | ((unsigned int)v[3] << 16);
            o.z = v[4] | ((unsigned int)v[5] << 16);
            o.w = v[6] | ((unsigned int)v[7] << 16);
            *(uint4*)(dst + j0) = o;
        }
    } else {
        // Q or K tile -> mrope then row write
        const int rr = tid >> 1, dh = (tid & 1) * 64;   // row, d-half
        const int s = s0 + rr;
        unsigned short* dst; float qsc;
        if (n0 < 1536) {
            dst = Q + (((size_t)b * NH_ + (n0 >> 7)) * S_ + s) * HD_ + dh;
            qsc = 0.1275174313431108f;     // 1/sqrt(128) * log2(e)
        } else {
            const int kv = (n0 - 1536) >> 7;
            dst = K + (((size_t)b * NKV_ + kv) * S_ + s) * HD_ + dh;
            qsc = 1.0f;
        }
        for (int j0 = 0; j0 < 64; j0 += 8) {
            // 8-chunks never cross mrope axis boundaries (16/40 are mult of 8)
            const int axis = (j0 < 16) ? 0 : (j0 < 40 ? 1 : 2);
            const size_t cidx = (((size_t)axis * B_ + b) * S_ + s) * HD_ + dh + j0;
            float cs[8], sn[8];
            if (flg) {
                const float4 ca_ = *(const float4*)((const float*)cosp + cidx);
                const float4 cb_ = *(const float4*)((const float*)cosp + cidx + 4);
                const float4 sa_ = *(const float4*)((const float*)sinp + cidx);
                const float4 sb_ = *(const float4*)((const float*)sinp + cidx + 4);
                cs[0]=ca_.x; cs[1]=ca_.y; cs[2]=ca_.z; cs[3]=ca_.w;
                cs[4]=cb_.x; cs[5]=cb_.y; cs[6]=cb_.z; cs[7]=cb_.w;
                sn[0]=sa_.x; sn[1]=sa_.y; sn[2]=sa_.z; sn[3]=sa_.w;
                sn[4]=sb_.x; sn[5]=sb_.y; sn[6]=sb_.z; sn[7]=sb_.w;
            } else {
                const unsigned short* cp = (const unsigned short*)cosp + cidx;
                const unsigned short* sp = (const unsigned short*)sinp + cidx;
#pragma unroll
                for (int j = 0; j < 8; j++) { cs[j] = bf2f(cp[j]); sn[j] = bf2f(sp[j]); }
            }
            const bf16x8 xc = *(const bf16x8*)&Ct[rr][dh + j0];
            const bf16x8 xp = *(const bf16x8*)&Ct[rr][(dh ^ 64) + j0];
            unsigned short v[8];
#pragma unroll
            for (int j = 0; j < 8; j++) {
                const float x = bf2f((unsigned short)xc[j]);
                const float p = bf2f((unsigned short)xp[j]);
                const float y = (dh == 0) ? (x * cs[j] - p * sn[j])
                                          : (x * cs[j] + p * sn[j]);
                v[j] = f2bf(y * qsc);
            }
            uint4 o;
            o.x = v[0] | ((unsigned int)v[1] << 16);
            o.y = v[2] | ((unsigned int)v[3] << 16);
            o.z = v[4] | ((unsigned int)v[5] << 16);
            o.w = v[6] | ((unsigned int)v[7] << 16);
            *(uint4*)(dst + j0) = o;
        }
    }
}

// 1-D grid 384 blocks; XCD-region remap; 3-buffer counted-vmcnt loop.
__global__ __launch_bounds__(256) void gemm_o(
    const unsigned short* __restrict__ hsorig,
    const unsigned short* __restrict__ A,   // attn_out [4096,1536] bf16
    const unsigned short* __restrict__ W,   // o_w bf16 [1536,1536]
    void* __restrict__ C)                   // out [4096,1536] bf16 or f32
{
    __shared__ char sm[49152];
    unsigned short (*As)[4096] = (unsigned short (*)[4096])sm;            // [3][4096]
    unsigned short (*Ws)[4096] = (unsigned short (*)[4096])(sm + 24576);  // [3][4096]
    const int flg = detect_flag(hsorig);
    const int tid = threadIdx.x;
    const int w = tid >> 6, lane = tid & 63, quad = lane >> 4, l16 = lane & 15;
    const int wr = w >> 1, wc = w & 1;
    const int bid = blockIdx.x;
    const int xcd = bid & 7, loc = bid >> 3;      // loc in [0,48)
    const int n0 = (loc % 12) * 128;
    const int m0 = (xcd * 4 + loc / 12) * 128;
    const unsigned short* Wp = W + (size_t)n0 * HID_;

    f32x4 acc[4][4];
#pragma unroll
    for (int i = 0; i < 4; i++)
#pragma unroll
        for (int j = 0; j < 4; j++) acc[i][j] = (f32x4)0.0f;

    const int c0 = w * 64, c1 = 256 + w * 64;
    const int ca = c0 + lane, cb = c1 + lane;
    const int rA0 = ca >> 2, pA0 = (ca & 3) * 8;
    const int rA1 = cb >> 2, pA1 = (cb & 3) * 8;

#define STAGEG(bufi, kt)                                                          \
    do {                                                                          \
        const int k0_ = (kt) * 32;                                                \
        gload_lds16(A  + (size_t)(m0 + rA0) * HID_ + k0_ + pA0, &As[bufi][c0*8]); \
        gload_lds16(A  + (size_t)(m0 + rA1) * HID_ + k0_ + pA1, &As[bufi][c1*8]); \
        gload_lds16(Wp + (size_t)rA0 * HID_ + k0_ + pA0, &Ws[bufi][c0*8]);        \
        gload_lds16(Wp + (size_t)rA1 * HID_ + k0_ + pA1, &Ws[bufi][c1*8]);        \
    } while (0)

    STAGEG(0, 0);
    STAGEG(1, 1);
    VM4();
    RBAR();

    int cur = 0;
    for (int kt = 0; kt < HID_ / 32; ++kt) {
        if (kt + 2 < HID_ / 32)
            STAGEG((cur + 2 >= 3 ? cur - 1 : cur + 2), kt + 2);

        bf16x8 a[4], b[4];
#pragma unroll
        for (int mi = 0; mi < 4; mi++)
            a[mi] = *(const bf16x8*)&As[cur][(wr * 64 + mi * 16 + l16) * 32 + quad * 8];
#pragma unroll
        for (int ni = 0; ni < 4; ni++)
            b[ni] = *(const bf16x8*)&Ws[cur][(wc * 64 + ni * 16 + l16) * 32 + quad * 8];
#pragma unroll
        for (int mi = 0; mi < 4; mi++)
#pragma unroll
            for (int ni = 0; ni < 4; ni++)
                acc[mi][ni] = __builtin_amdgcn_mfma_f32_16x16x32_bf16(a[mi], b[ni], acc[mi][ni], 0, 0, 0);

        if (kt + 2 < HID_ / 32) { VM4(); } else { VM0(); }
        RBAR();
        cur = (cur + 1 == 3) ? 0 : cur + 1;
    }
#undef STAGEG

#pragma unroll
    for (int mi = 0; mi < 4; mi++) {
        const int row = m0 + wr * 64 + mi * 16 + quad * 4;
#pragma unroll
        for (int ni = 0; ni < 4; ni++) {
            const int col = n0 + wc * 64 + ni * 16 + l16;
#pragma unroll
            for (int r = 0; r < 4; r++) {
                const size_t off = (size_t)(row + r) * HID_ + col;
                if (flg) ((float*)C)[off] = acc[mi][ni][r];
                else ((unsigned short*)C)[off] = f2bf(acc[mi][ni][r]);
            }
        }
    }
}

// ---------------------------------------------------------------------------
// Flash attention v6 (round-8 verified, 69.9 µs): v4 tile structure + SPLIT-K
// on heavy q-tiles. Grid (24, 48): y<32 -> qt = 16+(y>>1), chunk y&1 (f32
// partial O/m/l); y>=32 -> qt = 47-y, single chunk, direct output.
// ---------------------------------------------------------------------------
__global__ __launch_bounds__(256, 3) void attn_fwd(
    const unsigned short* __restrict__ Q,
    const unsigned short* __restrict__ K,
    const unsigned short* __restrict__ Vt,
    float* __restrict__ Opart0,          // [384][64][128] f32 (CV_HS reuse)
    float* __restrict__ Opart1,          // [384][64][128] f32 (d_out scratch)
    float* __restrict__ mlp,             // [384][2][2][64] f32 (m,l per chunk)
    unsigned short* __restrict__ Aout)   // [4096, 1536]
{
    __shared__ unsigned short Ks2[2][64 * 128];   // linear, swizzled content
    __shared__ unsigned short Vs1[128 * 64];      // linear, swizzled content

    const int tid = threadIdx.x;
    const int w = tid >> 6, lane = tid & 63, quad = lane >> 4, l16 = lane & 15;
    const int bh = blockIdx.x;              // 0..23
    const int y  = blockIdx.y;              // 0..47
    int qt, t0, t1, chunk; bool split;
    if (y < 32) {                            // heavy tiles, split in two
        split = true;
        qt = 16 + (y >> 1);
        chunk = y & 1;
        const int half = (qt + 1) >> 1;
        t0 = chunk ? half : 0;
        t1 = chunk ? (qt + 1) : half;
    } else {                                 // light tiles, single chunk
        split = false; chunk = 0;
        qt = 47 - y;
        t0 = 0; t1 = qt + 1;
    }
    const int h  = bh % NH_;
    const int b  = bh / NH_;
    const int kvh = h / GRP_;
    const int q0 = qt * 64;

    const unsigned short* Qp = Q  + (((size_t)b * NH_ + h) * S_ + q0) * HD_;
    const char* Kg = (const char*)(K  + ((size_t)b * NKV_ + kvh) * S_ * HD_);
    const char* Vg = (const char*)(Vt + ((size_t)b * NKV_ + kvh) * HD_ * S_);

    // Q fragments in registers: row q = l16, k-chunk quad*8 (B-operand of QK^T)
    bf16x8 aq[4];
    {
        const unsigned short* qr = Qp + (size_t)(w * 16 + l16) * HD_ + quad * 8;
#pragma unroll
        for (int ks = 0; ks < 4; ks++)
            aq[ks] = *(const bf16x8*)(qr + ks * 32);
    }

    // Per-lane pre-swizzled source byte offsets for the DMA chunks.
    int offK[4], offV[4];
#pragma unroll
    for (int i = 0; i < 4; i++) {
        const int cK = w * 4 + i;
        const int krow = cK * 4 + (lane >> 4);
        const int kc = (lane & 15) * 16;
        offK[i] = krow * 256 + (kc ^ ((krow & 7) << 4));
        const int cV = w * 4 + i;
        const int vrow = cV * 8 + (lane >> 3);
        const int vc = (lane & 7) * 16;
        offV[i] = vrow * 4096 + (vc ^ ((vrow & 7) << 4));
    }

#define STAGE_K(bufi, tt)                                                      \
    do {                                                                       \
        char* kd_ = (char*)&Ks2[bufi][0];                                      \
        _Pragma("unroll")                                                      \
        for (int i_ = 0; i_ < 4; i_++)                                         \
            gload_lds16b(Kg + (tt) * 16384 + offK[i_],                         \
                         kd_ + (w * 4 + i_) * 1024);                           \
    } while (0)
#define STAGE_V(tt)                                                            \
    do {                                                                       \
        char* vd_ = (char*)&Vs1[0];                                            \
        _Pragma("unroll")                                                      \
        for (int i_ = 0; i_ < 4; i_++)                                         \
            gload_lds16b(Vg + (tt) * 128 + offV[i_],                           \
                         vd_ + (w * 4 + i_) * 1024);                           \
    } while (0)

    f32x4 Ot[8];                         // O^T fragments: row d, col q=l16
#pragma unroll
    for (int i = 0; i < 8; i++) Ot[i] = (f32x4)0.0f;
    float m_st = -1e30f, l_st = 0.f;     // lane-local (q = l16)

    const int xorb = (l16 & 7) << 4;     // read-side swizzle (row&7 == l16&7)
    int cur = 0;

    STAGE_K(0, t0);
    __syncthreads();      // vmcnt(0) drain at barrier -> K[t0] staged

    for (int t = t0; t < t1; t++) {
        const int k0 = t * 64;
        STAGE_V(t);                                // lands at B1
        if (t + 1 < t1) STAGE_K(cur ^ 1, t + 1);   // lands at B1 (early, ok)

        const char* kb_ = (const char*)&Ks2[cur][0];

        // S^T = K * Q^T : rows k (A = K-frag), cols q (B = Q-frag).
        f32x4 Sf[4];
#pragma unroll
        for (int i = 0; i < 4; i++) Sf[i] = (f32x4)0.0f;
        __builtin_amdgcn_s_setprio(1);
#pragma unroll
        for (int ks = 0; ks < 4; ks++) {
#pragma unroll
            for (int ni = 0; ni < 4; ni++) {
                bf16x8 bk = *(const bf16x8*)(kb_ + (ni * 16 + l16) * 256 +
                                             ((ks * 64 + quad * 16) ^ xorb));
                Sf[ni] = __builtin_amdgcn_mfma_f32_16x16x32_bf16(bk, aq[ks], Sf[ni], 0, 0, 0);
            }
        }
        __builtin_amdgcn_s_setprio(0);

        // causal mask only on the diagonal tile (t == qt; never in chunk 0)
        if (t == qt) {
            const int qq = q0 + w * 16 + l16;
#pragma unroll
            for (int ni = 0; ni < 4; ni++)
#pragma unroll
                for (int r = 0; r < 4; r++) {
                    const int kk = k0 + ni * 16 + quad * 4 + r;
                    if (kk > qq) Sf[ni][r] = -1e9f;
                }
        }

        // lane-local online softmax (exp2 domain; log2e folded into Q)
        float mx = Sf[0][0];
#pragma unroll
        for (int ni = 0; ni < 4; ni++)
#pragma unroll
            for (int r = 0; r < 4; r++) mx = fmaxf(mx, Sf[ni][r]);
        mx = fmaxf(mx, __shfl_xor(mx, 16, 64));
        mx = fmaxf(mx, __shfl_xor(mx, 32, 64));
        const float mn = fmaxf(m_st, mx);
        const float alpha = exp2f(m_st - mn);
        m_st = mn;
        float ps = 0.f;
#pragma unroll
        for (int ni = 0; ni < 4; ni++)
#pragma unroll
            for (int r = 0; r < 4; r++) {
                const float p = exp2f(Sf[ni][r] - mn);
                Sf[ni][r] = p;
                ps += p;
            }
        ps += __shfl_xor(ps, 16, 64);
        ps += __shfl_xor(ps, 32, 64);
        l_st = l_st * alpha + ps;
#pragma unroll
        for (int di = 0; di < 8; di++)
#pragma unroll
            for (int r = 0; r < 4; r++) Ot[di][r] *= alpha;

        __syncthreads();   // B1: V[t] (and K[t+1]) landed

        // O^T += V^T * P^T  (A = V^T-frag from LDS, B = P^T from S^T C-frag)
        const char* vb_ = (const char*)&Vs1[0];
        __builtin_amdgcn_s_setprio(1);
#pragma unroll
        for (int ni = 0; ni < 4; ni++) {
            bf16x4 pa;
            pa[0] = (short)f2bf(Sf[ni][0]);
            pa[1] = (short)f2bf(Sf[ni][1]);
            pa[2] = (short)f2bf(Sf[ni][2]);
            pa[3] = (short)f2bf(Sf[ni][3]);
#pragma unroll
            for (int di = 0; di < 8; di++) {
                bf16x4 va = *(const bf16x4*)(vb_ + (di * 16 + l16) * 128 +
                                             ((ni * 32 + quad * 8) ^ xorb));
                Ot[di] = mfma16(va, pa, Ot[di]);
            }
        }
        __builtin_amdgcn_s_setprio(0);

        __syncthreads();   // B2: all Vs reads done before next STAGE_V
        cur ^= 1;
    }
#undef STAGE_K
#undef STAGE_V

    const int rowl = w * 16 + l16;           // local q-row (0..63)
    if (!split) {
        const float rl = 1.0f / l_st;
        const int qrow = q0 + rowl;
        unsigned short* dst = Aout + ((size_t)b * S_ + qrow) * HID_ + h * HD_;
#pragma unroll
        for (int di = 0; di < 8; di++) {
            ushort4 o;
            o.x = f2bf(Ot[di][0] * rl);
            o.y = f2bf(Ot[di][1] * rl);
            o.z = f2bf(Ot[di][2] * rl);
            o.w = f2bf(Ot[di][3] * rl);
            *(ushort4*)(dst + di * 16 + quad * 4) = o;
        }
    } else {
        const int pair = bh * 16 + (qt - 16);          // 0..383
        float* Ob = (chunk ? Opart1 : Opart0) + (size_t)pair * 8192;
#pragma unroll
        for (int di = 0; di < 8; di++)
            *(f32x4*)&Ob[rowl * 128 + di * 16 + quad * 4] = Ot[di];
        if (quad == 0) {
            mlp[pair * 256 + chunk * 128 + rowl]      = m_st;
            mlp[pair * 256 + chunk * 128 + 64 + rowl] = l_st;
        }
    }
}

// ---------------------------------------------------------------------------
// Combine the two split-K partials per heavy q-tile; write bf16 into Aout.
// ---------------------------------------------------------------------------
__global__ __launch_bounds__(256) void attn_combine(
    const float* __restrict__ Opart0, const float* __restrict__ Opart1,
    const float* __restrict__ mlp, unsigned short* __restrict__ Aout)
{
    const int pair = blockIdx.x;             // 0..383
    const int bh = pair >> 4;
    const int qt = 16 + (pair & 15);
    const int h = bh % NH_, b = bh / NH_;
    const int q0 = qt * 64;
    const int row = threadIdx.x >> 2;        // 0..63
    const int dseg = (threadIdx.x & 3) * 32; // 0,32,64,96

    const float m0 = mlp[pair * 256 + row],       l0 = mlp[pair * 256 + 64 + row];
    const float m1 = mlp[pair * 256 + 128 + row], l1 = mlp[pair * 256 + 192 + row];
    const float m = fmaxf(m0, m1);
    const float s0 = exp2f(m0 - m), s1 = exp2f(m1 - m);
    const float rl = 1.0f / (l0 * s0 + l1 * s1);

    const float* O0 = Opart0 + (size_t)pair * 8192 + row * 128 + dseg;
    const float* O1 = Opart1 + (size_t)pair * 8192 + row * 128 + dseg;
    unsigned short* dst = Aout + ((size_t)b * S_ + q0 + row) * HID_ + h * HD_ + dseg;
#pragma unroll
    for (int j = 0; j < 32; j += 4) {
        const float4 a = *(const float4*)(O0 + j);
        const float4 c = *(const float4*)(O1 + j);
        ushort4 o;
        o.x = f2bf((a.x * s0 + c.x * s1) * rl);
        o.y = f2bf((a.y * s0 + c.y * s1) * rl);
        o.z = f2bf((a.z * s0 + c.z * s1) * rl);
        o.w = f2bf((a.w * s0 + c.w * s1) * rl);
        *(ushort4*)(dst + j) = o;
    }
}

extern "C" void kernel_launch(void* const* d_in, const int* in_sizes, int n_in,
                              void* d_out, int out_size, void* d_ws, size_t ws_size,
                              hipStream_t stream) {
    const void* hs   = d_in[0];
    const void* qw   = d_in[1];
    const void* qb   = d_in[2];
    const void* kw   = d_in[3];
    const void* kb   = d_in[4];
    const void* vw   = d_in[5];
    const void* vb   = d_in[6];
    const void* ow   = d_in[7];
    const void* cosp = d_in[8];
    const void* sinp = d_in[9];

    unsigned short* conv = (unsigned short*)d_ws + 16;            // CV_TOT = 11796480
    unsigned short* Cqkv = conv + CV_TOT;                         // 8388608 (Ao)
    unsigned short* Qb   = Cqkv + (size_t)8388608;                // 6291456
    unsigned short* Kb   = Qb + (size_t)6291456;                  // 1048576
    unsigned short* Vtb  = Kb + (size_t)1048576;                  // 1048576
    unsigned short* Ao   = Cqkv;                                  // attn output
    // Split-K partials — all in memory dead at attn time, zero footprint growth:
    //   chunk0 -> dead CV_HS conv region (384*8192 f32 = 3,145,728 f32 exact)
    //   chunk1 -> d_out scratch (>= 12.58 MB for both output dtypes; consumed
    //             by attn_combine before gemm_o rewrites d_out)
    //   m/l    -> dead qw conv region (98,304 f32 of 2,359,296-short region)
    float* Opart0 = (float*)conv;
    float* Opart1 = (float*)d_out;
    float* mlp    = (float*)(conv + CV_QW);

    convert_inputs<<<(CV_TOT / 8 + 255) / 256, 256, 0, stream>>>(hs, qw, kw, vw, ow, conv);
    gemm_qkv<<<dim3(512), 256, 0, stream>>>((const unsigned short*)hs,
                                            conv + CV_HS, conv, qb, kb, vb,
                                            cosp, sinp, Qb, Kb, Vtb);
    attn_fwd<<<dim3(24, 48), 256, 0, stream>>>(Qb, Kb, Vtb, Opart0, Opart1, mlp, Ao);
    attn_combine<<<dim3(384), 256, 0, stream>>>(Opart0, Opart1, mlp, Ao);
    gemm_o<<<dim3(384), 256, 0, stream>>>((const unsigned short*)hs,
                                          Ao, conv + CV_OW, d_out);
}